// Round 2
// baseline (338.685 us; speedup 1.0000x reference)
//
#include <hip/hip_runtime.h>

// HierarchicalChronoFormer forward, MI355X (gfx950).
// B=8, S=4096, D=512, H=8, dk=64, BIN=64, NB=64, T_BINS=1000.

typedef __attribute__((ext_vector_type(8))) short bf16x8;
typedef __attribute__((ext_vector_type(4))) float f32x4;

#define DEVI __device__ __forceinline__

DEVI unsigned short f2bf(float f) {
  union { float f; unsigned u; } v; v.f = f;
  unsigned r = v.u + 0x7FFFu + ((v.u >> 16) & 1u);
  return (unsigned short)(r >> 16);
}
DEVI float bf2f(unsigned short u) {
  union { unsigned u; float f; } v; v.u = ((unsigned)u) << 16; return v.f;
}

#define GLOAD_LDS16(gp, lp) \
  __builtin_amdgcn_global_load_lds((const __attribute__((address_space(1))) void*)(gp), \
                                   (__attribute__((address_space(3))) void*)(lp), 16, 0, 0)

// ---------------- weight transpose-pack: Wt[n][k] = bf16(W[k][n]); all mats 512x512
struct TPackArgs { const float* s[8]; unsigned short* d[8]; };

__global__ __launch_bounds__(256) void k_tpack8(TPackArgs args) {
  __shared__ float tile[64][65];
  int mat = blockIdx.x >> 6;
  int tl = blockIdx.x & 63;
  const float* W = args.s[mat];
  unsigned short* Wt = args.d[mat];
  int n0 = (tl & 7) << 6, k0 = (tl >> 3) << 6;
  int t = threadIdx.x, j = t & 63, i0 = t >> 6;
#pragma unroll
  for (int rr = 0; rr < 16; ++rr) {
    int i = rr * 4 + i0;
    tile[i][j] = W[(size_t)(k0 + i) * 512 + n0 + j];
  }
  __syncthreads();
#pragma unroll
  for (int rr = 0; rr < 16; ++rr) {
    int i = rr * 4 + i0;
    Wt[(size_t)(n0 + i) * 512 + k0 + j] = f2bf(tile[j][i]);
  }
}

__global__ __launch_bounds__(256) void k_concat3(const float* __restrict__ a,
    const float* __restrict__ b, const float* __restrict__ c, float* __restrict__ o) {
  int i = blockIdx.x * 256 + threadIdx.x;  // grid 6 -> i < 1536
  float v = (i < 512) ? a[i] : (i < 1024) ? b[i - 512] : c[i - 1024];
  o[i] = v;
}

// ---------------- abs_t = cumsum(max(td,0)) per batch row
__global__ __launch_bounds__(64) void k_cumsum(const float* __restrict__ td, float* __restrict__ abs_t) {
  int b = blockIdx.x, lane = threadIdx.x;
  const float* row = td + (size_t)b * 4096;
  float* out = abs_t + (size_t)b * 4096;
  float carry = 0.f;
  for (int c = 0; c < 64; ++c) {
    float v = fmaxf(row[c * 64 + lane], 0.f);
#pragma unroll
    for (int off = 1; off < 64; off <<= 1) {
      float n = __shfl_up(v, off, 64);
      if (lane >= off) v += n;
    }
    out[c * 64 + lane] = carry + v;
    carry += __shfl(v, 63, 64);
  }
}

// ---------------- bin stats: bin_abs -> bin_rel, bin_mask, last_idx
__global__ __launch_bounds__(64) void k_binstats(const int* __restrict__ x, const float* __restrict__ abs_t,
    float* __restrict__ bin_rel, int* __restrict__ bin_mask, int* __restrict__ last_idx) {
  int b = blockIdx.x, lane = threadIdx.x;
  __shared__ float babs[64];
  __shared__ int bmask[64];
  for (int nb = 0; nb < 64; ++nb) {
    int gt = b * 4096 + nb * 64 + lane;
    int valid = x[gt] != 0;
    float a = valid ? abs_t[gt] : 0.f;
#pragma unroll
    for (int off = 32; off; off >>= 1) a = fmaxf(a, __shfl_xor(a, off, 64));
    unsigned long long bal = __ballot(valid);
    if (lane == 0) { babs[nb] = a; bmask[nb] = (bal != 0ULL) ? 1 : 0; }
  }
  __syncthreads();
  float rel = (lane == 0) ? 0.f : fmaxf(babs[lane] - babs[lane - 1], 0.f);
  bin_rel[b * 64 + lane] = rel;
  bin_mask[b * 64 + lane] = bmask[lane];
  unsigned long long bal = __ballot(bmask[lane] != 0);
  if (lane == 0) last_idx[b] = max(__popcll(bal) - 1, 0);
}

// ---------------- h = ee[x] (0 if x==0) + emb_rel[rb] + emb_abs[ab], bf16 out
__global__ __launch_bounds__(256) void k_embed(const int* __restrict__ x, const float* __restrict__ td,
    const float* __restrict__ abs_t, const float* __restrict__ ee, const float* __restrict__ er,
    const float* __restrict__ ea, unsigned short* __restrict__ h) {
  int t = threadIdx.x;
  int tok = blockIdx.x * 4 + (t >> 6);
  int lane = t & 63;
  int c0 = lane * 8;
  int xi = x[tok];
  int rb = (int)td[tok]; rb = min(max(rb, 0), 999);
  int ab = (int)abs_t[tok]; ab = min(max(ab, 0), 999);
  const f32x4* pr = (const f32x4*)(er + (size_t)rb * 512 + c0);
  const f32x4* pa = (const f32x4*)(ea + (size_t)ab * 512 + c0);
  f32x4 s0 = pr[0] + pa[0];
  f32x4 s1 = pr[1] + pa[1];
  if (xi != 0) {
    const f32x4* pe = (const f32x4*)(ee + (size_t)xi * 512 + c0);
    s0 += pe[0]; s1 += pe[1];
  }
  bf16x8 o;
#pragma unroll
  for (int i = 0; i < 4; ++i) { o[i] = (short)f2bf(s0[i]); o[4 + i] = (short)f2bf(s1[i]); }
  *(bf16x8*)(h + (size_t)tok * 512 + c0) = o;
}

// ---------------- GEMM: C[M,N] = A[M,512](bf16) @ Wt[N,512]^T(bf16) + bias[N], bf16 out
// m97 structure: 128x128 tile, BK=64, global_load_lds width-16, linear LDS, 2-barrier loop.
__global__ __launch_bounds__(256) void k_gemm(const unsigned short* __restrict__ A,
    const unsigned short* __restrict__ Wt, const float* __restrict__ bias,
    unsigned short* __restrict__ Cout, int N, int tiles_n) {
  __shared__ unsigned short As[128 * 64];
  __shared__ unsigned short Bs[128 * 64];
  int bx = blockIdx.x % tiles_n;
  int by = blockIdx.x / tiles_n;
  int m0 = by << 7, n0 = bx << 7;
  int t = threadIdx.x;
  int lane = t & 63, w = t >> 6;
  int wm = w >> 1, wn = w & 1;
  f32x4 acc[4][4] = {};
  for (int k0 = 0; k0 < 512; k0 += 64) {
    __syncthreads();  // previous tile's ds_reads done before overwrite
#pragma unroll
    for (int i = 0; i < 4; ++i) {
      int idx = i * 256 + t;
      int row = idx >> 3, seg = idx & 7;
      GLOAD_LDS16(&A[(size_t)(m0 + row) * 512 + k0 + seg * 8], &As[idx * 8]);
      GLOAD_LDS16(&Wt[(size_t)(n0 + row) * 512 + k0 + seg * 8], &Bs[idx * 8]);
    }
    __syncthreads();  // compiler drains vmcnt before barrier
#pragma unroll
    for (int ks = 0; ks < 2; ++ks) {
      bf16x8 af[4], bb[4];
#pragma unroll
      for (int i = 0; i < 4; ++i) {
        af[i] = *(const bf16x8*)&As[(wm * 64 + i * 16 + (lane & 15)) * 64 + ks * 32 + (lane >> 4) * 8];
        bb[i] = *(const bf16x8*)&Bs[(wn * 64 + i * 16 + (lane & 15)) * 64 + ks * 32 + (lane >> 4) * 8];
      }
#pragma unroll
      for (int i = 0; i < 4; ++i)
#pragma unroll
        for (int j = 0; j < 4; ++j)
          acc[i][j] = __builtin_amdgcn_mfma_f32_16x16x32_bf16(af[i], bb[j], acc[i][j], 0, 0, 0);
    }
  }
#pragma unroll
  for (int i = 0; i < 4; ++i) {
    int rowb = m0 + wm * 64 + i * 16 + ((lane >> 4) << 2);
#pragma unroll
    for (int j = 0; j < 4; ++j) {
      int col = n0 + wn * 64 + j * 16 + (lane & 15);
      float bv = bias[col];
#pragma unroll
      for (int r = 0; r < 4; ++r)
        Cout[(size_t)(rowb + r) * N + col] = f2bf(acc[i][j][r] + bv);
    }
  }
}

// ---------------- fused attention; block = 4 heads of one 64-token bin (2 blocks/bin).
// qkv row layout [1536]: q at col h*64, k at 512+h*64, v at 1024+h*64.
__global__ __launch_bounds__(256) void k_attn(const unsigned short* __restrict__ qkv,
    const float* __restrict__ td, const int* __restrict__ validv,
    const float* __restrict__ temb, unsigned short* __restrict__ ctx) {
  __shared__ float bias_s[4][64];
  __shared__ int valid_s[64];
  __shared__ unsigned short P_s[4][64][72];
  __shared__ unsigned short Vt_s[4][64][72];
  int blk = blockIdx.x >> 1, hg = blockIdx.x & 1;
  int t = threadIdx.x, hl = t >> 6, lane = t & 63;
  int h = hg * 4 + hl;
  size_t base = (size_t)blk * 64;
  if (t < 64) {
    valid_s[t] = (validv[base + t] != 0) ? 1 : 0;
    int tb = (int)td[base + t];
    tb = min(max(tb, 0), 999);
#pragma unroll
    for (int hh = 0; hh < 4; ++hh) bias_s[hh][t] = temb[tb * 8 + hg * 4 + hh];
  }
  {  // stage V transposed: Vt[feat][key]; lane = key
    const unsigned short* vp = qkv + (base + lane) * 1536 + 1024 + h * 64;
#pragma unroll
    for (int f8 = 0; f8 < 8; ++f8) {
      bf16x8 v8 = *(const bf16x8*)(vp + f8 * 8);
#pragma unroll
      for (int j = 0; j < 8; ++j) Vt_s[hl][f8 * 8 + j][lane] = (unsigned short)v8[j];
    }
  }
  __syncthreads();
  bf16x8 qa[2][4], kb[2][4];
#pragma unroll
  for (int ks = 0; ks < 2; ++ks)
#pragma unroll
    for (int i = 0; i < 4; ++i) {
      int row = i * 16 + (lane & 15);
      int kk = ks * 32 + (lane >> 4) * 8;
      qa[ks][i] = *(const bf16x8*)&qkv[(base + row) * 1536 + h * 64 + kk];
      kb[ks][i] = *(const bf16x8*)&qkv[(base + row) * 1536 + 512 + h * 64 + kk];
    }
  f32x4 acc[4][4] = {};
#pragma unroll
  for (int ks = 0; ks < 2; ++ks)
#pragma unroll
    for (int i = 0; i < 4; ++i)
#pragma unroll
      for (int j = 0; j < 4; ++j)
        acc[i][j] = __builtin_amdgcn_mfma_f32_16x16x32_bf16(qa[ks][i], kb[ks][j], acc[i][j], 0, 0, 0);
  // masked+biased softmax over keys; row r held by 16-lane group, 4 frag-cols
#pragma unroll
  for (int i = 0; i < 4; ++i) {
#pragma unroll
    for (int r = 0; r < 4; ++r) {
      float sv[4];
#pragma unroll
      for (int j = 0; j < 4; ++j) {
        int key = j * 16 + (lane & 15);
        float s = acc[i][j][r] * 0.125f;
        sv[j] = valid_s[key] ? (s + bias_s[hl][key]) : -1e9f;
      }
      float m = fmaxf(fmaxf(sv[0], sv[1]), fmaxf(sv[2], sv[3]));
#pragma unroll
      for (int off = 1; off < 16; off <<= 1) m = fmaxf(m, __shfl_xor(m, off, 64));
      float p[4], sum = 0.f;
#pragma unroll
      for (int j = 0; j < 4; ++j) { p[j] = __expf(sv[j] - m); sum += p[j]; }
#pragma unroll
      for (int off = 1; off < 16; off <<= 1) sum += __shfl_xor(sum, off, 64);
      float inv = 1.f / sum;
      int row = i * 16 + ((lane >> 4) << 2) + r;
#pragma unroll
      for (int j = 0; j < 4; ++j) P_s[hl][row][j * 16 + (lane & 15)] = f2bf(p[j] * inv);
    }
  }
  __syncthreads();
  f32x4 acc2[4][4] = {};
#pragma unroll
  for (int ks = 0; ks < 2; ++ks) {
    bf16x8 pa[4], vb[4];
    int kk = ks * 32 + (lane >> 4) * 8;
#pragma unroll
    for (int i = 0; i < 4; ++i) {
      pa[i] = *(const bf16x8*)&P_s[hl][i * 16 + (lane & 15)][kk];
      vb[i] = *(const bf16x8*)&Vt_s[hl][i * 16 + (lane & 15)][kk];
    }
#pragma unroll
    for (int i = 0; i < 4; ++i)
#pragma unroll
      for (int j = 0; j < 4; ++j)
        acc2[i][j] = __builtin_amdgcn_mfma_f32_16x16x32_bf16(pa[i], vb[j], acc2[i][j], 0, 0, 0);
  }
#pragma unroll
  for (int i = 0; i < 4; ++i) {
    int rowb = i * 16 + ((lane >> 4) << 2);
#pragma unroll
    for (int j = 0; j < 4; ++j) {
      int col = h * 64 + j * 16 + (lane & 15);
#pragma unroll
      for (int r = 0; r < 4; ++r)
        ctx[(base + rowb + r) * 512 + col] = f2bf(acc2[i][j][r]);
    }
  }
}

// ---------------- LayerNorm rows of X[*,512] (bf16 in); POOL=1: masked mean-pool -> bf16[512]
// POOL=0: f32 out rows.
template<int POOL>
__global__ __launch_bounds__(256) void k_lnpool(const unsigned short* __restrict__ X,
    const float* __restrict__ g, const float* __restrict__ bt,
    const int* __restrict__ validv, void* __restrict__ out) {
  __shared__ float pool_s[4][512];
  __shared__ int cnt_s[4];
  int blk = blockIdx.x;
  int t = threadIdx.x, w = t >> 6, lane = t & 63;
  float gv[8], bv[8];
#pragma unroll
  for (int i = 0; i < 8; ++i) { gv[i] = g[lane * 8 + i]; bv[i] = bt[lane * 8 + i]; }
  float psum[8] = {0.f, 0.f, 0.f, 0.f, 0.f, 0.f, 0.f, 0.f};
  int cnt = 0;
  for (int r0 = 0; r0 < 16; ++r0) {
    int row = blk * 64 + w * 16 + r0;
    bf16x8 xv = *(const bf16x8*)(X + (size_t)row * 512 + lane * 8);
    float xa[8];
#pragma unroll
    for (int i = 0; i < 8; ++i) xa[i] = bf2f((unsigned short)xv[i]);
    float s = 0.f;
#pragma unroll
    for (int i = 0; i < 8; ++i) s += xa[i];
#pragma unroll
    for (int off = 1; off < 64; off <<= 1) s += __shfl_xor(s, off, 64);
    float mean = s * (1.f / 512.f);
    float vsum = 0.f;
#pragma unroll
    for (int i = 0; i < 8; ++i) { float d = xa[i] - mean; vsum += d * d; }
#pragma unroll
    for (int off = 1; off < 64; off <<= 1) vsum += __shfl_xor(vsum, off, 64);
    float rstd = rsqrtf(vsum * (1.f / 512.f) + 1e-5f);
    if (POOL) {
      if (validv[row] != 0) {
        cnt++;
#pragma unroll
        for (int i = 0; i < 8; ++i) psum[i] += (xa[i] - mean) * rstd * gv[i] + bv[i];
      }
    } else {
      f32x4 y0, y1;
#pragma unroll
      for (int i = 0; i < 4; ++i) {
        y0[i] = (xa[i] - mean) * rstd * gv[i] + bv[i];
        y1[i] = (xa[4 + i] - mean) * rstd * gv[4 + i] + bv[4 + i];
      }
      float* op = (float*)out + (size_t)row * 512 + lane * 8;
      *(f32x4*)op = y0; *(f32x4*)(op + 4) = y1;
    }
  }
  if (POOL) {
#pragma unroll
    for (int i = 0; i < 8; ++i) pool_s[w][lane * 8 + i] = psum[i];
    if (lane == 0) cnt_s[w] = cnt;
    __syncthreads();
    int total = cnt_s[0] + cnt_s[1] + cnt_s[2] + cnt_s[3];
    float denom = fmaxf((float)total, 1.f);
    for (int c = t; c < 512; c += 256) {
      float v = (pool_s[0][c] + pool_s[1][c] + pool_s[2][c] + pool_s[3][c]) / denom;
      ((unsigned short*)out)[(size_t)blk * 512 + c] = f2bf(v);
    }
  }
}

// ---------------- final: pick last row, MLP, sigmoid. grid 8 (one block per batch).
__global__ __launch_bounds__(256) void k_final(const float* __restrict__ h_inter,
    const int* __restrict__ last_idx, const float* __restrict__ w1, const float* __restrict__ b1,
    const float* __restrict__ w2, const float* __restrict__ b2, float* __restrict__ outp) {
  __shared__ float row_s[512];
  __shared__ float red_s[4];
  int b = blockIdx.x, t = threadIdx.x;
  const float* rp = h_inter + (size_t)(b * 64 + last_idx[b]) * 512;
  row_s[t] = rp[t];
  row_s[t + 256] = rp[t + 256];
  __syncthreads();
  float acc = b1[t];
  for (int k = 0; k < 512; ++k) acc += row_s[k] * w1[(size_t)k * 256 + t];
  float hv = fmaxf(acc, 0.f) * w2[t];
#pragma unroll
  for (int off = 1; off < 64; off <<= 1) hv += __shfl_xor(hv, off, 64);
  if ((t & 63) == 0) red_s[t >> 6] = hv;
  __syncthreads();
  if (t == 0) {
    float o = red_s[0] + red_s[1] + red_s[2] + red_s[3] + b2[0];
    outp[b] = 1.f / (1.f + __expf(-o));
  }
}

extern "C" void kernel_launch(void* const* d_in, const int* in_sizes, int n_in,
                              void* d_out, int out_size, void* d_ws, size_t ws_size,
                              hipStream_t stream) {
  const int*   x    = (const int*)d_in[0];
  const float* td   = (const float*)d_in[1];
  const float* ee   = (const float*)d_in[2];
  const float* er   = (const float*)d_in[3];
  const float* ea   = (const float*)d_in[4];
  const float* iq_w = (const float*)d_in[5];  const float* iq_b = (const float*)d_in[6];
  const float* ik_w = (const float*)d_in[7];  const float* ik_b = (const float*)d_in[8];
  const float* iv_w = (const float*)d_in[9];  const float* iv_b = (const float*)d_in[10];
  const float* io_w = (const float*)d_in[11]; const float* io_b = (const float*)d_in[12];
  const float* eq_w = (const float*)d_in[13]; const float* eq_b = (const float*)d_in[14];
  const float* ek_w = (const float*)d_in[15]; const float* ek_b = (const float*)d_in[16];
  const float* ev_w = (const float*)d_in[17]; const float* ev_b = (const float*)d_in[18];
  const float* eo_w = (const float*)d_in[19]; const float* eo_b = (const float*)d_in[20];
  const float* i_temb = (const float*)d_in[21];
  const float* e_temb = (const float*)d_in[22];
  const float* i_g  = (const float*)d_in[23]; const float* i_bt = (const float*)d_in[24];
  const float* e_g  = (const float*)d_in[25]; const float* e_bt = (const float*)d_in[26];
  const float* w1   = (const float*)d_in[27]; const float* b1   = (const float*)d_in[28];
  const float* w2   = (const float*)d_in[29]; const float* b2   = (const float*)d_in[30];

  char* ws = (char*)d_ws;
  size_t off = 0;
  auto alloc = [&](size_t nb) { size_t r = off; off += (nb + 255) & ~(size_t)255; return r; };
  float* abs_t    = (float*)(ws + alloc((size_t)32768 * 4));
  float* bin_rel  = (float*)(ws + alloc(512 * 4));
  int*   bin_mask = (int*)(ws + alloc(512 * 4));
  int*   last_idx = (int*)(ws + alloc(64));
  unsigned short* wqkv_i = (unsigned short*)(ws + alloc((size_t)1536 * 512 * 2));
  unsigned short* wo_i   = (unsigned short*)(ws + alloc((size_t)512 * 512 * 2));
  unsigned short* wqkv_e = (unsigned short*)(ws + alloc((size_t)1536 * 512 * 2));
  unsigned short* wo_e   = (unsigned short*)(ws + alloc((size_t)512 * 512 * 2));
  float* bqkv_i = (float*)(ws + alloc(1536 * 4));
  float* bqkv_e = (float*)(ws + alloc(1536 * 4));
  unsigned short* hbuf = (unsigned short*)(ws + alloc((size_t)32768 * 512 * 2));   // h, then ctx
  char* big = ws + alloc((size_t)32768 * 1536 * 2);                                // qkv bf16, then proj bf16
  unsigned short* qkvbuf = (unsigned short*)big;
  unsigned short* projbuf = (unsigned short*)big;
  unsigned short* bin_repr = (unsigned short*)(ws + alloc((size_t)512 * 512 * 2));
  char* small = ws + alloc((size_t)512 * 1536 * 2);                                // qkv2 bf16, then proj2 bf16
  unsigned short* qkv2 = (unsigned short*)small;
  unsigned short* proj2 = (unsigned short*)small;
  unsigned short* ctx2 = (unsigned short*)(ws + alloc((size_t)512 * 512 * 2));
  float* h_inter = (float*)(ws + alloc((size_t)512 * 512 * 4));

  // 1. pack weights (bf16, transposed) + concat qkv biases
  TPackArgs tp;
  tp.s[0] = iq_w; tp.d[0] = wqkv_i;
  tp.s[1] = ik_w; tp.d[1] = wqkv_i + (size_t)512 * 512;
  tp.s[2] = iv_w; tp.d[2] = wqkv_i + (size_t)1024 * 512;
  tp.s[3] = io_w; tp.d[3] = wo_i;
  tp.s[4] = eq_w; tp.d[4] = wqkv_e;
  tp.s[5] = ek_w; tp.d[5] = wqkv_e + (size_t)512 * 512;
  tp.s[6] = ev_w; tp.d[6] = wqkv_e + (size_t)1024 * 512;
  tp.s[7] = eo_w; tp.d[7] = wo_e;
  k_tpack8<<<512, 256, 0, stream>>>(tp);
  k_concat3<<<6, 256, 0, stream>>>(iq_b, ik_b, iv_b, bqkv_i);
  k_concat3<<<6, 256, 0, stream>>>(eq_b, ek_b, ev_b, bqkv_e);

  // 2. time features
  k_cumsum<<<8, 64, 0, stream>>>(td, abs_t);
  k_binstats<<<8, 64, 0, stream>>>(x, abs_t, bin_rel, bin_mask, last_idx);

  // 3. embeddings -> h (bf16)
  k_embed<<<8192, 256, 0, stream>>>(x, td, abs_t, ee, er, ea, hbuf);

  // 4. intra path
  k_gemm<<<256 * 12, 256, 0, stream>>>(hbuf, wqkv_i, bqkv_i, qkvbuf, 1536, 12);
  k_attn<<<1024, 256, 0, stream>>>(qkvbuf, td, x, i_temb, hbuf);                   // ctx -> hbuf
  k_gemm<<<256 * 4, 256, 0, stream>>>(hbuf, wo_i, io_b, projbuf, 512, 4);          // proj over qkv region
  k_lnpool<1><<<512, 256, 0, stream>>>(projbuf, i_g, i_bt, x, bin_repr);

  // 5. inter path
  k_gemm<<<4 * 12, 256, 0, stream>>>(bin_repr, wqkv_e, bqkv_e, qkv2, 1536, 12);
  k_attn<<<16, 256, 0, stream>>>(qkv2, bin_rel, bin_mask, e_temb, ctx2);
  k_gemm<<<4 * 4, 256, 0, stream>>>(ctx2, wo_e, eo_b, proj2, 512, 4);              // proj2 over qkv2 region
  k_lnpool<0><<<8, 256, 0, stream>>>(proj2, e_g, e_bt, nullptr, h_inter);

  // 6. head
  k_final<<<8, 256, 0, stream>>>(h_inter, last_idx, w1, b1, w2, b2, (float*)d_out);
}

// Round 3
// 302.424 us; speedup vs baseline: 1.1199x; 1.1199x over previous
//
#include <hip/hip_runtime.h>

// HierarchicalChronoFormer forward, MI355X (gfx950).
// B=8, S=4096, D=512, H=8, dk=64, BIN=64, NB=64, T_BINS=1000.

typedef __attribute__((ext_vector_type(8))) short bf16x8;
typedef __attribute__((ext_vector_type(4))) float f32x4;

#define DEVI __device__ __forceinline__

DEVI unsigned short f2bf(float f) {
  union { float f; unsigned u; } v; v.f = f;
  unsigned r = v.u + 0x7FFFu + ((v.u >> 16) & 1u);
  return (unsigned short)(r >> 16);
}
DEVI float bf2f(unsigned short u) {
  union { unsigned u; float f; } v; v.u = ((unsigned)u) << 16; return v.f;
}

#define GLOAD_LDS16(gp, lp) \
  __builtin_amdgcn_global_load_lds((const __attribute__((address_space(1))) void*)(gp), \
                                   (__attribute__((address_space(3))) void*)(lp), 16, 0, 0)

// ---------------- weight transpose-pack: Wt[n][k] = bf16(W[k][n]); all mats 512x512
struct TPackArgs { const float* s[8]; unsigned short* d[8]; };

__global__ __launch_bounds__(256) void k_tpack8(TPackArgs args) {
  __shared__ float tile[64][65];
  int mat = blockIdx.x >> 6;
  int tl = blockIdx.x & 63;
  const float* W = args.s[mat];
  unsigned short* Wt = args.d[mat];
  int n0 = (tl & 7) << 6, k0 = (tl >> 3) << 6;
  int t = threadIdx.x, j = t & 63, i0 = t >> 6;
#pragma unroll
  for (int rr = 0; rr < 16; ++rr) {
    int i = rr * 4 + i0;
    tile[i][j] = W[(size_t)(k0 + i) * 512 + n0 + j];
  }
  __syncthreads();
#pragma unroll
  for (int rr = 0; rr < 16; ++rr) {
    int i = rr * 4 + i0;
    Wt[(size_t)(n0 + i) * 512 + k0 + j] = f2bf(tile[j][i]);
  }
}

__global__ __launch_bounds__(256) void k_concat3(const float* __restrict__ a,
    const float* __restrict__ b, const float* __restrict__ c, float* __restrict__ o) {
  int i = blockIdx.x * 256 + threadIdx.x;  // grid 6 -> i < 1536
  float v = (i < 512) ? a[i] : (i < 1024) ? b[i - 512] : c[i - 1024];
  o[i] = v;
}

// ---------------- abs_t = cumsum(max(td,0)) per batch row
__global__ __launch_bounds__(64) void k_cumsum(const float* __restrict__ td, float* __restrict__ abs_t) {
  int b = blockIdx.x, lane = threadIdx.x;
  const float* row = td + (size_t)b * 4096;
  float* out = abs_t + (size_t)b * 4096;
  float carry = 0.f;
  for (int c = 0; c < 64; ++c) {
    float v = fmaxf(row[c * 64 + lane], 0.f);
#pragma unroll
    for (int off = 1; off < 64; off <<= 1) {
      float n = __shfl_up(v, off, 64);
      if (lane >= off) v += n;
    }
    out[c * 64 + lane] = carry + v;
    carry += __shfl(v, 63, 64);
  }
}

// ---------------- bin stats: bin_abs -> bin_rel, bin_mask, last_idx
__global__ __launch_bounds__(64) void k_binstats(const int* __restrict__ x, const float* __restrict__ abs_t,
    float* __restrict__ bin_rel, int* __restrict__ bin_mask, int* __restrict__ last_idx) {
  int b = blockIdx.x, lane = threadIdx.x;
  __shared__ float babs[64];
  __shared__ int bmask[64];
  for (int nb = 0; nb < 64; ++nb) {
    int gt = b * 4096 + nb * 64 + lane;
    int valid = x[gt] != 0;
    float a = valid ? abs_t[gt] : 0.f;
#pragma unroll
    for (int off = 32; off; off >>= 1) a = fmaxf(a, __shfl_xor(a, off, 64));
    unsigned long long bal = __ballot(valid);
    if (lane == 0) { babs[nb] = a; bmask[nb] = (bal != 0ULL) ? 1 : 0; }
  }
  __syncthreads();
  float rel = (lane == 0) ? 0.f : fmaxf(babs[lane] - babs[lane - 1], 0.f);
  bin_rel[b * 64 + lane] = rel;
  bin_mask[b * 64 + lane] = bmask[lane];
  unsigned long long bal = __ballot(bmask[lane] != 0);
  if (lane == 0) last_idx[b] = max(__popcll(bal) - 1, 0);
}

// ---------------- h = ee[x] (0 if x==0) + emb_rel[rb] + emb_abs[ab], bf16 out
__global__ __launch_bounds__(256) void k_embed(const int* __restrict__ x, const float* __restrict__ td,
    const float* __restrict__ abs_t, const float* __restrict__ ee, const float* __restrict__ er,
    const float* __restrict__ ea, unsigned short* __restrict__ h) {
  int t = threadIdx.x;
  int tok = blockIdx.x * 4 + (t >> 6);
  int lane = t & 63;
  int c0 = lane * 8;
  int xi = x[tok];
  int rb = (int)td[tok]; rb = min(max(rb, 0), 999);
  int ab = (int)abs_t[tok]; ab = min(max(ab, 0), 999);
  const f32x4* pr = (const f32x4*)(er + (size_t)rb * 512 + c0);
  const f32x4* pa = (const f32x4*)(ea + (size_t)ab * 512 + c0);
  f32x4 s0 = pr[0] + pa[0];
  f32x4 s1 = pr[1] + pa[1];
  if (xi != 0) {
    const f32x4* pe = (const f32x4*)(ee + (size_t)xi * 512 + c0);
    s0 += pe[0]; s1 += pe[1];
  }
  bf16x8 o;
#pragma unroll
  for (int i = 0; i < 4; ++i) { o[i] = (short)f2bf(s0[i]); o[4 + i] = (short)f2bf(s1[i]); }
  *(bf16x8*)(h + (size_t)tok * 512 + c0) = o;
}

// ---------------- big GEMM: C[M,N] = A[M,512] @ Wt[N,512]^T + bias, bf16 out.
// 256x256 tile, BK=64, 8 waves (2Mx4N), dbuf-2 LDS, global_load_lds + both-sides
// XOR swizzle (T2), counted vmcnt(8) (T3/T4), setprio around MFMA clusters (T5),
// XCD-aware block swizzle (T1). K fixed at 512 (nt=8).
DEVI bf16x8 lds_frag(const unsigned short* buf, int row, int sc) {
  return *(const bf16x8*)&buf[row * 64 + (sc ^ ((row & 7) << 3))];
}

template<int SWZ>
__global__ __launch_bounds__(512, 2) void k_gemm256(const unsigned short* __restrict__ A,
    const unsigned short* __restrict__ Wt, const float* __restrict__ bias,
    unsigned short* __restrict__ Cout, int N, int tiles_n) {
  __shared__ unsigned short lds[2][2][256 * 64];  // [buf][A=0/B=1]
  int bid = blockIdx.x;
  if (SWZ) { int q = (int)gridDim.x >> 3; bid = (bid & 7) * q + (bid >> 3); }
  int by = bid / tiles_n, bx = bid % tiles_n;
  int m0 = by << 8, n0 = bx << 8;
  int t = threadIdx.x;
  int lane = t & 63, w = t >> 6;
  int wm = w >> 2, wn = w & 3;            // wave tile: rows wm*128..+127, cols wn*64..+63
  int l15 = lane & 15, l4 = lane >> 4;

  // stage K-tile kt into buffer c (8 x global_load_lds per thread, source pre-swizzled)
  auto stage = [&](int kt, int c) {
    int k0 = kt << 6;
#pragma unroll
    for (int l = 0; l < 4; ++l) {
      int idx = l * 512 + t;
      int row = idx >> 3, seg = (idx & 7) ^ (row & 7);
      GLOAD_LDS16(&A[(size_t)(m0 + row) * 512 + k0 + seg * 8], &lds[c][0][idx * 8]);
    }
#pragma unroll
    for (int l = 0; l < 4; ++l) {
      int idx = l * 512 + t;
      int row = idx >> 3, seg = (idx & 7) ^ (row & 7);
      GLOAD_LDS16(&Wt[(size_t)(n0 + row) * 512 + k0 + seg * 8], &lds[c][1][idx * 8]);
    }
  };

  f32x4 acc[8][4] = {};
  stage(0, 0);
  stage(1, 1);
  const int nt = 8;
  for (int kt = 0; kt < nt; ++kt) {
    int c = kt & 1;
    const unsigned short* As = lds[c][0];
    const unsigned short* Bs = lds[c][1];
    if (kt < nt - 1) asm volatile("s_waitcnt vmcnt(8)" ::: "memory");
    else             asm volatile("s_waitcnt vmcnt(0)" ::: "memory");
    __builtin_amdgcn_s_barrier();

    bf16x8 af[4][2], b0[2][2], b1[2][2];
    // ---- phase 0: mh=0, nh=0 (loads A rows 0..63 of wave tile + B cols 0..31)
#pragma unroll
    for (int i = 0; i < 4; ++i)
#pragma unroll
      for (int ks = 0; ks < 2; ++ks)
        af[i][ks] = lds_frag(As, wm * 128 + i * 16 + l15, ks * 32 + l4 * 8);
#pragma unroll
    for (int j = 0; j < 2; ++j)
#pragma unroll
      for (int ks = 0; ks < 2; ++ks)
        b0[j][ks] = lds_frag(Bs, wn * 64 + j * 16 + l15, ks * 32 + l4 * 8);
    __builtin_amdgcn_s_barrier();
    __builtin_amdgcn_s_setprio(1);
#pragma unroll
    for (int i = 0; i < 4; ++i)
#pragma unroll
      for (int j = 0; j < 2; ++j)
#pragma unroll
        for (int ks = 0; ks < 2; ++ks)
          acc[i][j] = __builtin_amdgcn_mfma_f32_16x16x32_bf16(af[i][ks], b0[j][ks], acc[i][j], 0, 0, 0);
    __builtin_amdgcn_s_setprio(0);
    __builtin_amdgcn_s_barrier();
    // ---- phase 1: mh=0, nh=1 (loads B cols 32..63)
#pragma unroll
    for (int j = 0; j < 2; ++j)
#pragma unroll
      for (int ks = 0; ks < 2; ++ks)
        b1[j][ks] = lds_frag(Bs, wn * 64 + 32 + j * 16 + l15, ks * 32 + l4 * 8);
    __builtin_amdgcn_s_barrier();
    __builtin_amdgcn_s_setprio(1);
#pragma unroll
    for (int i = 0; i < 4; ++i)
#pragma unroll
      for (int j = 0; j < 2; ++j)
#pragma unroll
        for (int ks = 0; ks < 2; ++ks)
          acc[i][2 + j] = __builtin_amdgcn_mfma_f32_16x16x32_bf16(af[i][ks], b1[j][ks], acc[i][2 + j], 0, 0, 0);
    __builtin_amdgcn_s_setprio(0);
    __builtin_amdgcn_s_barrier();
    // ---- phase 2: mh=1, nh=1 (loads A rows 64..127 of wave tile)
#pragma unroll
    for (int i = 0; i < 4; ++i)
#pragma unroll
      for (int ks = 0; ks < 2; ++ks)
        af[i][ks] = lds_frag(As, wm * 128 + 64 + i * 16 + l15, ks * 32 + l4 * 8);
    __builtin_amdgcn_s_barrier();
    __builtin_amdgcn_s_setprio(1);
#pragma unroll
    for (int i = 0; i < 4; ++i)
#pragma unroll
      for (int j = 0; j < 2; ++j)
#pragma unroll
        for (int ks = 0; ks < 2; ++ks)
          acc[4 + i][2 + j] = __builtin_amdgcn_mfma_f32_16x16x32_bf16(af[i][ks], b1[j][ks], acc[4 + i][2 + j], 0, 0, 0);
    __builtin_amdgcn_s_setprio(0);
    __builtin_amdgcn_s_barrier();
    // ---- phase 3: mh=1, nh=0 (no loads, b0 still resident)
    __builtin_amdgcn_s_setprio(1);
#pragma unroll
    for (int i = 0; i < 4; ++i)
#pragma unroll
      for (int j = 0; j < 2; ++j)
#pragma unroll
        for (int ks = 0; ks < 2; ++ks)
          acc[4 + i][j] = __builtin_amdgcn_mfma_f32_16x16x32_bf16(af[i][ks], b0[j][ks], acc[4 + i][j], 0, 0, 0);
    __builtin_amdgcn_s_setprio(0);
    __builtin_amdgcn_s_barrier();   // all waves done reading buf c
    if (kt + 2 < nt) stage(kt + 2, c);
  }
  // epilogue: bias + bf16 store
#pragma unroll
  for (int i = 0; i < 8; ++i) {
    int rowb = m0 + wm * 128 + i * 16 + (l4 << 2);
#pragma unroll
    for (int j = 0; j < 4; ++j) {
      int col = n0 + wn * 64 + j * 16 + l15;
      float bv = bias[col];
#pragma unroll
      for (int r = 0; r < 4; ++r)
        Cout[(size_t)(rowb + r) * N + col] = f2bf(acc[i][j][r] + bv);
    }
  }
}

// ---------------- small GEMM (inter path): 128x128 tile, reg-staged padded LDS.
__global__ __launch_bounds__(256) void k_gemm(const unsigned short* __restrict__ A,
    const unsigned short* __restrict__ Wt, const float* __restrict__ bias,
    unsigned short* __restrict__ Cout, int N, int tiles_n) {
  __shared__ unsigned short As[128 * 72];
  __shared__ unsigned short Bs[128 * 72];
  int bx = blockIdx.x % tiles_n;
  int by = blockIdx.x / tiles_n;
  int m0 = by << 7, n0 = bx << 7;
  int t = threadIdx.x;
  int lane = t & 63, w = t >> 6;
  int wm = w >> 1, wn = w & 1;
  f32x4 acc[4][4] = {};
  for (int k0 = 0; k0 < 512; k0 += 64) {
    __syncthreads();
#pragma unroll
    for (int i = 0; i < 4; ++i) {
      int idx = t + i * 256;
      int row = idx >> 3, seg = idx & 7;
      *(bf16x8*)&As[row * 72 + seg * 8] = *(const bf16x8*)&A[(size_t)(m0 + row) * 512 + k0 + seg * 8];
      *(bf16x8*)&Bs[row * 72 + seg * 8] = *(const bf16x8*)&Wt[(size_t)(n0 + row) * 512 + k0 + seg * 8];
    }
    __syncthreads();
#pragma unroll
    for (int ks = 0; ks < 2; ++ks) {
      bf16x8 af[4], bb[4];
#pragma unroll
      for (int i = 0; i < 4; ++i) {
        af[i] = *(const bf16x8*)&As[(wm * 64 + i * 16 + (lane & 15)) * 72 + ks * 32 + (lane >> 4) * 8];
        bb[i] = *(const bf16x8*)&Bs[(wn * 64 + i * 16 + (lane & 15)) * 72 + ks * 32 + (lane >> 4) * 8];
      }
#pragma unroll
      for (int i = 0; i < 4; ++i)
#pragma unroll
        for (int j = 0; j < 4; ++j)
          acc[i][j] = __builtin_amdgcn_mfma_f32_16x16x32_bf16(af[i], bb[j], acc[i][j], 0, 0, 0);
    }
  }
#pragma unroll
  for (int i = 0; i < 4; ++i) {
    int rowb = m0 + wm * 64 + i * 16 + ((lane >> 4) << 2);
#pragma unroll
    for (int j = 0; j < 4; ++j) {
      int col = n0 + wn * 64 + j * 16 + (lane & 15);
      float bv = bias[col];
#pragma unroll
      for (int r = 0; r < 4; ++r)
        Cout[(size_t)(rowb + r) * N + col] = f2bf(acc[i][j][r] + bv);
    }
  }
}

// ---------------- fused attention; block = 4 heads of one 64-token bin (2 blocks/bin).
// qkv row layout [1536]: q at col h*64, k at 512+h*64, v at 1024+h*64.
__global__ __launch_bounds__(256) void k_attn(const unsigned short* __restrict__ qkv,
    const float* __restrict__ td, const int* __restrict__ validv,
    const float* __restrict__ temb, unsigned short* __restrict__ ctx) {
  __shared__ float bias_s[4][64];
  __shared__ int valid_s[64];
  __shared__ unsigned short P_s[4][64][72];
  __shared__ unsigned short Vt_s[4][64][72];
  int blk = blockIdx.x >> 1, hg = blockIdx.x & 1;
  int t = threadIdx.x, hl = t >> 6, lane = t & 63;
  int h = hg * 4 + hl;
  size_t base = (size_t)blk * 64;
  if (t < 64) {
    valid_s[t] = (validv[base + t] != 0) ? 1 : 0;
    int tb = (int)td[base + t];
    tb = min(max(tb, 0), 999);
#pragma unroll
    for (int hh = 0; hh < 4; ++hh) bias_s[hh][t] = temb[tb * 8 + hg * 4 + hh];
  }
  {  // stage V transposed: Vt[feat][key]; lane = key
    const unsigned short* vp = qkv + (base + lane) * 1536 + 1024 + h * 64;
#pragma unroll
    for (int f8 = 0; f8 < 8; ++f8) {
      bf16x8 v8 = *(const bf16x8*)(vp + f8 * 8);
#pragma unroll
      for (int j = 0; j < 8; ++j) Vt_s[hl][f8 * 8 + j][lane] = (unsigned short)v8[j];
    }
  }
  __syncthreads();
  bf16x8 qa[2][4], kb[2][4];
#pragma unroll
  for (int ks = 0; ks < 2; ++ks)
#pragma unroll
    for (int i = 0; i < 4; ++i) {
      int row = i * 16 + (lane & 15);
      int kk = ks * 32 + (lane >> 4) * 8;
      qa[ks][i] = *(const bf16x8*)&qkv[(base + row) * 1536 + h * 64 + kk];
      kb[ks][i] = *(const bf16x8*)&qkv[(base + row) * 1536 + 512 + h * 64 + kk];
    }
  f32x4 acc[4][4] = {};
#pragma unroll
  for (int ks = 0; ks < 2; ++ks)
#pragma unroll
    for (int i = 0; i < 4; ++i)
#pragma unroll
      for (int j = 0; j < 4; ++j)
        acc[i][j] = __builtin_amdgcn_mfma_f32_16x16x32_bf16(qa[ks][i], kb[ks][j], acc[i][j], 0, 0, 0);
  // masked+biased softmax over keys; row r held by 16-lane group, 4 frag-cols
#pragma unroll
  for (int i = 0; i < 4; ++i) {
#pragma unroll
    for (int r = 0; r < 4; ++r) {
      float sv[4];
#pragma unroll
      for (int j = 0; j < 4; ++j) {
        int key = j * 16 + (lane & 15);
        float s = acc[i][j][r] * 0.125f;
        sv[j] = valid_s[key] ? (s + bias_s[hl][key]) : -1e9f;
      }
      float m = fmaxf(fmaxf(sv[0], sv[1]), fmaxf(sv[2], sv[3]));
#pragma unroll
      for (int off = 1; off < 16; off <<= 1) m = fmaxf(m, __shfl_xor(m, off, 64));
      float p[4], sum = 0.f;
#pragma unroll
      for (int j = 0; j < 4; ++j) { p[j] = __expf(sv[j] - m); sum += p[j]; }
#pragma unroll
      for (int off = 1; off < 16; off <<= 1) sum += __shfl_xor(sum, off, 64);
      float inv = 1.f / sum;
      int row = i * 16 + ((lane >> 4) << 2) + r;
#pragma unroll
      for (int j = 0; j < 4; ++j) P_s[hl][row][j * 16 + (lane & 15)] = f2bf(p[j] * inv);
    }
  }
  __syncthreads();
  f32x4 acc2[4][4] = {};
#pragma unroll
  for (int ks = 0; ks < 2; ++ks) {
    bf16x8 pa[4], vb[4];
    int kk = ks * 32 + (lane >> 4) * 8;
#pragma unroll
    for (int i = 0; i < 4; ++i) {
      pa[i] = *(const bf16x8*)&P_s[hl][i * 16 + (lane & 15)][kk];
      vb[i] = *(const bf16x8*)&Vt_s[hl][i * 16 + (lane & 15)][kk];
    }
#pragma unroll
    for (int i = 0; i < 4; ++i)
#pragma unroll
      for (int j = 0; j < 4; ++j)
        acc2[i][j] = __builtin_amdgcn_mfma_f32_16x16x32_bf16(pa[i], vb[j], acc2[i][j], 0, 0, 0);
  }
#pragma unroll
  for (int i = 0; i < 4; ++i) {
    int rowb = i * 16 + ((lane >> 4) << 2);
#pragma unroll
    for (int j = 0; j < 4; ++j) {
      int col = h * 64 + j * 16 + (lane & 15);
#pragma unroll
      for (int r = 0; r < 4; ++r)
        ctx[(base + rowb + r) * 512 + col] = f2bf(acc2[i][j][r]);
    }
  }
}

// ---------------- LayerNorm rows of X[*,512] (bf16 in); POOL=1: masked mean-pool -> bf16[512]
// POOL=0: f32 out rows.
template<int POOL>
__global__ __launch_bounds__(256) void k_lnpool(const unsigned short* __restrict__ X,
    const float* __restrict__ g, const float* __restrict__ bt,
    const int* __restrict__ validv, void* __restrict__ out) {
  __shared__ float pool_s[4][512];
  __shared__ int cnt_s[4];
  int blk = blockIdx.x;
  int t = threadIdx.x, w = t >> 6, lane = t & 63;
  float gv[8], bv[8];
#pragma unroll
  for (int i = 0; i < 8; ++i) { gv[i] = g[lane * 8 + i]; bv[i] = bt[lane * 8 + i]; }
  float psum[8] = {0.f, 0.f, 0.f, 0.f, 0.f, 0.f, 0.f, 0.f};
  int cnt = 0;
  for (int r0 = 0; r0 < 16; ++r0) {
    int row = blk * 64 + w * 16 + r0;
    bf16x8 xv = *(const bf16x8*)(X + (size_t)row * 512 + lane * 8);
    float xa[8];
#pragma unroll
    for (int i = 0; i < 8; ++i) xa[i] = bf2f((unsigned short)xv[i]);
    float s = 0.f;
#pragma unroll
    for (int i = 0; i < 8; ++i) s += xa[i];
#pragma unroll
    for (int off = 1; off < 64; off <<= 1) s += __shfl_xor(s, off, 64);
    float mean = s * (1.f / 512.f);
    float vsum = 0.f;
#pragma unroll
    for (int i = 0; i < 8; ++i) { float d = xa[i] - mean; vsum += d * d; }
#pragma unroll
    for (int off = 1; off < 64; off <<= 1) vsum += __shfl_xor(vsum, off, 64);
    float rstd = rsqrtf(vsum * (1.f / 512.f) + 1e-5f);
    if (POOL) {
      if (validv[row] != 0) {
        cnt++;
#pragma unroll
        for (int i = 0; i < 8; ++i) psum[i] += (xa[i] - mean) * rstd * gv[i] + bv[i];
      }
    } else {
      f32x4 y0, y1;
#pragma unroll
      for (int i = 0; i < 4; ++i) {
        y0[i] = (xa[i] - mean) * rstd * gv[i] + bv[i];
        y1[i] = (xa[4 + i] - mean) * rstd * gv[4 + i] + bv[4 + i];
      }
      float* op = (float*)out + (size_t)row * 512 + lane * 8;
      *(f32x4*)op = y0; *(f32x4*)(op + 4) = y1;
    }
  }
  if (POOL) {
#pragma unroll
    for (int i = 0; i < 8; ++i) pool_s[w][lane * 8 + i] = psum[i];
    if (lane == 0) cnt_s[w] = cnt;
    __syncthreads();
    int total = cnt_s[0] + cnt_s[1] + cnt_s[2] + cnt_s[3];
    float denom = fmaxf((float)total, 1.f);
    for (int c = t; c < 512; c += 256) {
      float v = (pool_s[0][c] + pool_s[1][c] + pool_s[2][c] + pool_s[3][c]) / denom;
      ((unsigned short*)out)[(size_t)blk * 512 + c] = f2bf(v);
    }
  }
}

// ---------------- final: pick last row, MLP, sigmoid. grid 8 (one block per batch).
__global__ __launch_bounds__(256) void k_final(const float* __restrict__ h_inter,
    const int* __restrict__ last_idx, const float* __restrict__ w1, const float* __restrict__ b1,
    const float* __restrict__ w2, const float* __restrict__ b2, float* __restrict__ outp) {
  __shared__ float row_s[512];
  __shared__ float red_s[4];
  int b = blockIdx.x, t = threadIdx.x;
  const float* rp = h_inter + (size_t)(b * 64 + last_idx[b]) * 512;
  row_s[t] = rp[t];
  row_s[t + 256] = rp[t + 256];
  __syncthreads();
  float acc = b1[t];
  for (int k = 0; k < 512; ++k) acc += row_s[k] * w1[(size_t)k * 256 + t];
  float hv = fmaxf(acc, 0.f) * w2[t];
#pragma unroll
  for (int off = 1; off < 64; off <<= 1) hv += __shfl_xor(hv, off, 64);
  if ((t & 63) == 0) red_s[t >> 6] = hv;
  __syncthreads();
  if (t == 0) {
    float o = red_s[0] + red_s[1] + red_s[2] + red_s[3] + b2[0];
    outp[b] = 1.f / (1.f + __expf(-o));
  }
}

extern "C" void kernel_launch(void* const* d_in, const int* in_sizes, int n_in,
                              void* d_out, int out_size, void* d_ws, size_t ws_size,
                              hipStream_t stream) {
  const int*   x    = (const int*)d_in[0];
  const float* td   = (const float*)d_in[1];
  const float* ee   = (const float*)d_in[2];
  const float* er   = (const float*)d_in[3];
  const float* ea   = (const float*)d_in[4];
  const float* iq_w = (const float*)d_in[5];  const float* iq_b = (const float*)d_in[6];
  const float* ik_w = (const float*)d_in[7];  const float* ik_b = (const float*)d_in[8];
  const float* iv_w = (const float*)d_in[9];  const float* iv_b = (const float*)d_in[10];
  const float* io_w = (const float*)d_in[11]; const float* io_b = (const float*)d_in[12];
  const float* eq_w = (const float*)d_in[13]; const float* eq_b = (const float*)d_in[14];
  const float* ek_w = (const float*)d_in[15]; const float* ek_b = (const float*)d_in[16];
  const float* ev_w = (const float*)d_in[17]; const float* ev_b = (const float*)d_in[18];
  const float* eo_w = (const float*)d_in[19]; const float* eo_b = (const float*)d_in[20];
  const float* i_temb = (const float*)d_in[21];
  const float* e_temb = (const float*)d_in[22];
  const float* i_g  = (const float*)d_in[23]; const float* i_bt = (const float*)d_in[24];
  const float* e_g  = (const float*)d_in[25]; const float* e_bt = (const float*)d_in[26];
  const float* w1   = (const float*)d_in[27]; const float* b1   = (const float*)d_in[28];
  const float* w2   = (const float*)d_in[29]; const float* b2   = (const float*)d_in[30];

  char* ws = (char*)d_ws;
  size_t off = 0;
  auto alloc = [&](size_t nb) { size_t r = off; off += (nb + 255) & ~(size_t)255; return r; };
  float* abs_t    = (float*)(ws + alloc((size_t)32768 * 4));
  float* bin_rel  = (float*)(ws + alloc(512 * 4));
  int*   bin_mask = (int*)(ws + alloc(512 * 4));
  int*   last_idx = (int*)(ws + alloc(64));
  unsigned short* wqkv_i = (unsigned short*)(ws + alloc((size_t)1536 * 512 * 2));
  unsigned short* wo_i   = (unsigned short*)(ws + alloc((size_t)512 * 512 * 2));
  unsigned short* wqkv_e = (unsigned short*)(ws + alloc((size_t)1536 * 512 * 2));
  unsigned short* wo_e   = (unsigned short*)(ws + alloc((size_t)512 * 512 * 2));
  float* bqkv_i = (float*)(ws + alloc(1536 * 4));
  float* bqkv_e = (float*)(ws + alloc(1536 * 4));
  unsigned short* hbuf = (unsigned short*)(ws + alloc((size_t)32768 * 512 * 2));   // h, then ctx
  char* big = ws + alloc((size_t)32768 * 1536 * 2);                                // qkv bf16, then proj bf16
  unsigned short* qkvbuf = (unsigned short*)big;
  unsigned short* projbuf = (unsigned short*)big;
  unsigned short* bin_repr = (unsigned short*)(ws + alloc((size_t)512 * 512 * 2));
  char* small = ws + alloc((size_t)512 * 1536 * 2);                                // qkv2 bf16, then proj2 bf16
  unsigned short* qkv2 = (unsigned short*)small;
  unsigned short* proj2 = (unsigned short*)small;
  unsigned short* ctx2 = (unsigned short*)(ws + alloc((size_t)512 * 512 * 2));
  float* h_inter = (float*)(ws + alloc((size_t)512 * 512 * 4));

  // 1. pack weights (bf16, transposed) + concat qkv biases
  TPackArgs tp;
  tp.s[0] = iq_w; tp.d[0] = wqkv_i;
  tp.s[1] = ik_w; tp.d[1] = wqkv_i + (size_t)512 * 512;
  tp.s[2] = iv_w; tp.d[2] = wqkv_i + (size_t)1024 * 512;
  tp.s[3] = io_w; tp.d[3] = wo_i;
  tp.s[4] = eq_w; tp.d[4] = wqkv_e;
  tp.s[5] = ek_w; tp.d[5] = wqkv_e + (size_t)512 * 512;
  tp.s[6] = ev_w; tp.d[6] = wqkv_e + (size_t)1024 * 512;
  tp.s[7] = eo_w; tp.d[7] = wo_e;
  k_tpack8<<<512, 256, 0, stream>>>(tp);
  k_concat3<<<6, 256, 0, stream>>>(iq_b, ik_b, iv_b, bqkv_i);
  k_concat3<<<6, 256, 0, stream>>>(eq_b, ek_b, ev_b, bqkv_e);

  // 2. time features
  k_cumsum<<<8, 64, 0, stream>>>(td, abs_t);
  k_binstats<<<8, 64, 0, stream>>>(x, abs_t, bin_rel, bin_mask, last_idx);

  // 3. embeddings -> h (bf16)
  k_embed<<<8192, 256, 0, stream>>>(x, td, abs_t, ee, er, ea, hbuf);

  // 4. intra path (256^2 8-wave GEMMs with XCD swizzle; grids 768 and 256, %8==0)
  k_gemm256<1><<<128 * 6, 512, 0, stream>>>(hbuf, wqkv_i, bqkv_i, qkvbuf, 1536, 6);
  k_attn<<<1024, 256, 0, stream>>>(qkvbuf, td, x, i_temb, hbuf);                   // ctx -> hbuf
  k_gemm256<1><<<128 * 2, 512, 0, stream>>>(hbuf, wo_i, io_b, projbuf, 512, 2);    // proj over qkv region
  k_lnpool<1><<<512, 256, 0, stream>>>(projbuf, i_g, i_bt, x, bin_repr);

  // 5. inter path (small: 128^2 reg-staged GEMM)
  k_gemm<<<4 * 12, 256, 0, stream>>>(bin_repr, wqkv_e, bqkv_e, qkv2, 1536, 12);
  k_attn<<<16, 256, 0, stream>>>(qkv2, bin_rel, bin_mask, e_temb, ctx2);
  k_gemm<<<4 * 4, 256, 0, stream>>>(ctx2, wo_e, eo_b, proj2, 512, 4);              // proj2 over qkv2 region
  k_lnpool<0><<<8, 256, 0, stream>>>(proj2, e_g, e_bt, nullptr, h_inter);

  // 6. head
  k_final<<<8, 256, 0, stream>>>(h_inter, last_idx, w1, b1, w2, b2, (float*)d_out);
}

// Round 4
// 266.874 us; speedup vs baseline: 1.2691x; 1.1332x over previous
//
#include <hip/hip_runtime.h>

// HierarchicalChronoFormer forward, MI355X (gfx950).
// B=8, S=4096, D=512, H=8, dk=64, BIN=64, NB=64, T_BINS=1000.

typedef __attribute__((ext_vector_type(8))) short bf16x8;
typedef __attribute__((ext_vector_type(4))) float f32x4;

#define DEVI __device__ __forceinline__

DEVI unsigned short f2bf(float f) {
  union { float f; unsigned u; } v; v.f = f;
  unsigned r = v.u + 0x7FFFu + ((v.u >> 16) & 1u);
  return (unsigned short)(r >> 16);
}
DEVI float bf2f(unsigned short u) {
  union { unsigned u; float f; } v; v.u = ((unsigned)u) << 16; return v.f;
}

#define GLOAD_LDS16(gp, lp) \
  __builtin_amdgcn_global_load_lds((const __attribute__((address_space(1))) void*)(gp), \
                                   (__attribute__((address_space(3))) void*)(lp), 16, 0, 0)

// ---------------- weight transpose-pack: Wt[n][k] = bf16(W[k][n]); all mats 512x512
struct TPackArgs { const float* s[8]; unsigned short* d[8]; };

__global__ __launch_bounds__(256) void k_tpack8(TPackArgs args) {
  __shared__ float tile[64][65];
  int mat = blockIdx.x >> 6;
  int tl = blockIdx.x & 63;
  const float* W = args.s[mat];
  unsigned short* Wt = args.d[mat];
  int n0 = (tl & 7) << 6, k0 = (tl >> 3) << 6;
  int t = threadIdx.x, j = t & 63, i0 = t >> 6;
#pragma unroll
  for (int rr = 0; rr < 16; ++rr) {
    int i = rr * 4 + i0;
    tile[i][j] = W[(size_t)(k0 + i) * 512 + n0 + j];
  }
  __syncthreads();
#pragma unroll
  for (int rr = 0; rr < 16; ++rr) {
    int i = rr * 4 + i0;
    Wt[(size_t)(n0 + i) * 512 + k0 + j] = f2bf(tile[j][i]);
  }
}

// ---------------- both qkv bias concats in one kernel (grid 6)
__global__ __launch_bounds__(256) void k_bias2(const float* __restrict__ a0,
    const float* __restrict__ b0, const float* __restrict__ c0,
    const float* __restrict__ a1, const float* __restrict__ b1, const float* __restrict__ c1,
    float* __restrict__ o0, float* __restrict__ o1) {
  int i = blockIdx.x * 256 + threadIdx.x;  // < 1536
  o0[i] = (i < 512) ? a0[i] : (i < 1024) ? b0[i - 512] : c0[i - 1024];
  o1[i] = (i < 512) ? a1[i] : (i < 1024) ? b1[i - 512] : c1[i - 1024];
}

// ---------------- fused time features: abs_t cumsum + per-bin stats (one pass)
__global__ __launch_bounds__(64) void k_time(const float* __restrict__ td, const int* __restrict__ x,
    float* __restrict__ abs_t, float* __restrict__ bin_rel, int* __restrict__ bin_mask,
    int* __restrict__ last_idx) {
  int b = blockIdx.x, lane = threadIdx.x;
  const float* row = td + (size_t)b * 4096;
  const int* xr = x + (size_t)b * 4096;
  float* out = abs_t + (size_t)b * 4096;
  __shared__ float babs[64];
  __shared__ int bmask[64];
  float carry = 0.f;
  for (int c = 0; c < 64; ++c) {
    float v = fmaxf(row[c * 64 + lane], 0.f);
#pragma unroll
    for (int off = 1; off < 64; off <<= 1) {
      float n = __shfl_up(v, off, 64);
      if (lane >= off) v += n;
    }
    float a = carry + v;
    out[c * 64 + lane] = a;
    carry += __shfl(v, 63, 64);
    int valid = xr[c * 64 + lane] != 0;
    float am = valid ? a : 0.f;
#pragma unroll
    for (int off = 32; off; off >>= 1) am = fmaxf(am, __shfl_xor(am, off, 64));
    unsigned long long bal = __ballot(valid);
    if (lane == 0) { babs[c] = am; bmask[c] = (bal != 0ULL) ? 1 : 0; }
  }
  __syncthreads();
  float rel = (lane == 0) ? 0.f : fmaxf(babs[lane] - babs[lane - 1], 0.f);
  bin_rel[b * 64 + lane] = rel;
  bin_mask[b * 64 + lane] = bmask[lane];
  unsigned long long bal = __ballot(bmask[lane] != 0);
  if (lane == 0) last_idx[b] = max(__popcll(bal) - 1, 0);
}

// ---------------- h = ee[x] (0 if x==0) + emb_rel[rb] + emb_abs[ab], bf16 out
__global__ __launch_bounds__(256) void k_embed(const int* __restrict__ x, const float* __restrict__ td,
    const float* __restrict__ abs_t, const float* __restrict__ ee, const float* __restrict__ er,
    const float* __restrict__ ea, unsigned short* __restrict__ h) {
  int t = threadIdx.x;
  int tok = blockIdx.x * 4 + (t >> 6);
  int lane = t & 63;
  int c0 = lane * 8;
  int xi = x[tok];
  int rb = (int)td[tok]; rb = min(max(rb, 0), 999);
  int ab = (int)abs_t[tok]; ab = min(max(ab, 0), 999);
  const f32x4* pr = (const f32x4*)(er + (size_t)rb * 512 + c0);
  const f32x4* pa = (const f32x4*)(ea + (size_t)ab * 512 + c0);
  f32x4 s0 = pr[0] + pa[0];
  f32x4 s1 = pr[1] + pa[1];
  if (xi != 0) {
    const f32x4* pe = (const f32x4*)(ee + (size_t)xi * 512 + c0);
    s0 += pe[0]; s1 += pe[1];
  }
  bf16x8 o;
#pragma unroll
  for (int i = 0; i < 4; ++i) { o[i] = (short)f2bf(s0[i]); o[4 + i] = (short)f2bf(s1[i]); }
  *(bf16x8*)(h + (size_t)tok * 512 + c0) = o;
}

// ---------------- big GEMM: C[M,N] = A[M,512] @ Wt[N,512]^T + bias, bf16 out.
// 256x256 tile, BK=64, 8 waves (2Mx4N), dbuf-2 LDS, global_load_lds + both-sides
// XOR swizzle (T2), counted vmcnt(8) (T4), 2 super-phases/K-tile (32 MFMA per
// barrier pair), setprio (T5), bijective XCD swizzle (T1).
DEVI bf16x8 lds_frag(const unsigned short* buf, int row, int sc) {
  return *(const bf16x8*)&buf[row * 64 + (sc ^ ((row & 7) << 3))];
}

__global__ __launch_bounds__(512, 2) void k_gemm256(const unsigned short* __restrict__ A,
    const unsigned short* __restrict__ Wt, const float* __restrict__ bias,
    unsigned short* __restrict__ Cout, int N, int tiles_n) {
  __shared__ unsigned short lds[2][2][256 * 64];  // [buf][A=0/B=1]
  int bid = blockIdx.x;
  { int q = (int)gridDim.x >> 3; bid = (bid & 7) * q + (bid >> 3); }  // grid % 8 == 0
  int by = bid / tiles_n, bx = bid % tiles_n;
  int m0 = by << 8, n0 = bx << 8;
  int t = threadIdx.x;
  int lane = t & 63, w = t >> 6;
  int wm = w >> 2, wn = w & 3;            // wave tile: rows wm*128..+127, cols wn*64..+63
  int l15 = lane & 15, l4 = lane >> 4;

  auto stage = [&](int kt, int c) {
    int k0 = kt << 6;
#pragma unroll
    for (int l = 0; l < 4; ++l) {
      int idx = l * 512 + t;
      int row = idx >> 3, seg = (idx & 7) ^ (row & 7);
      GLOAD_LDS16(&A[(size_t)(m0 + row) * 512 + k0 + seg * 8], &lds[c][0][idx * 8]);
    }
#pragma unroll
    for (int l = 0; l < 4; ++l) {
      int idx = l * 512 + t;
      int row = idx >> 3, seg = (idx & 7) ^ (row & 7);
      GLOAD_LDS16(&Wt[(size_t)(n0 + row) * 512 + k0 + seg * 8], &lds[c][1][idx * 8]);
    }
  };

  f32x4 acc[8][4] = {};
  stage(0, 0);
  stage(1, 1);
  const int nt = 8;
  for (int kt = 0; kt < nt; ++kt) {
    int c = kt & 1;
    const unsigned short* As = lds[c][0];
    const unsigned short* Bs = lds[c][1];
    if (kt < nt - 1) asm volatile("s_waitcnt vmcnt(8)" ::: "memory");
    else             asm volatile("s_waitcnt vmcnt(0)" ::: "memory");
    __builtin_amdgcn_s_barrier();

    // ---- super-phase 0: A rows 0..63 of wave tile x all 64 cols (32 MFMA)
    bf16x8 af[4][2], bb[4][2];
#pragma unroll
    for (int i = 0; i < 4; ++i)
#pragma unroll
      for (int ks = 0; ks < 2; ++ks)
        af[i][ks] = lds_frag(As, wm * 128 + i * 16 + l15, ks * 32 + l4 * 8);
#pragma unroll
    for (int j = 0; j < 4; ++j)
#pragma unroll
      for (int ks = 0; ks < 2; ++ks)
        bb[j][ks] = lds_frag(Bs, wn * 64 + j * 16 + l15, ks * 32 + l4 * 8);
    __builtin_amdgcn_sched_barrier(0);
    __builtin_amdgcn_s_barrier();
    asm volatile("s_waitcnt lgkmcnt(0)" ::: "memory");
    __builtin_amdgcn_sched_barrier(0);
    __builtin_amdgcn_s_setprio(1);
#pragma unroll
    for (int i = 0; i < 4; ++i)
#pragma unroll
      for (int j = 0; j < 4; ++j)
#pragma unroll
        for (int ks = 0; ks < 2; ++ks)
          acc[i][j] = __builtin_amdgcn_mfma_f32_16x16x32_bf16(af[i][ks], bb[j][ks], acc[i][j], 0, 0, 0);
    __builtin_amdgcn_s_setprio(0);
    __builtin_amdgcn_s_barrier();

    // ---- super-phase 1: A rows 64..127 of wave tile x all 64 cols (32 MFMA)
    bf16x8 ah[4][2];
#pragma unroll
    for (int i = 0; i < 4; ++i)
#pragma unroll
      for (int ks = 0; ks < 2; ++ks)
        ah[i][ks] = lds_frag(As, wm * 128 + 64 + i * 16 + l15, ks * 32 + l4 * 8);
    __builtin_amdgcn_sched_barrier(0);
    __builtin_amdgcn_s_barrier();
    asm volatile("s_waitcnt lgkmcnt(0)" ::: "memory");
    __builtin_amdgcn_sched_barrier(0);
    __builtin_amdgcn_s_setprio(1);
#pragma unroll
    for (int i = 0; i < 4; ++i)
#pragma unroll
      for (int j = 0; j < 4; ++j)
#pragma unroll
        for (int ks = 0; ks < 2; ++ks)
          acc[4 + i][j] = __builtin_amdgcn_mfma_f32_16x16x32_bf16(ah[i][ks], bb[j][ks], acc[4 + i][j], 0, 0, 0);
    __builtin_amdgcn_s_setprio(0);
    __builtin_amdgcn_s_barrier();   // all waves done reading buf c
    if (kt + 2 < nt) stage(kt + 2, c);
  }
  // epilogue: bias + bf16 store
#pragma unroll
  for (int i = 0; i < 8; ++i) {
    int rowb = m0 + wm * 128 + i * 16 + (l4 << 2);
#pragma unroll
    for (int j = 0; j < 4; ++j) {
      int col = n0 + wn * 64 + j * 16 + l15;
      float bv = bias[col];
#pragma unroll
      for (int r = 0; r < 4; ++r)
        Cout[(size_t)(rowb + r) * N + col] = f2bf(acc[i][j][r] + bv);
    }
  }
}

// ---------------- small GEMM (inter path): 128x128 tile, reg-staged padded LDS.
__global__ __launch_bounds__(256) void k_gemm(const unsigned short* __restrict__ A,
    const unsigned short* __restrict__ Wt, const float* __restrict__ bias,
    unsigned short* __restrict__ Cout, int N, int tiles_n) {
  __shared__ unsigned short As[128 * 72];
  __shared__ unsigned short Bs[128 * 72];
  int bx = blockIdx.x % tiles_n;
  int by = blockIdx.x / tiles_n;
  int m0 = by << 7, n0 = bx << 7;
  int t = threadIdx.x;
  int lane = t & 63, w = t >> 6;
  int wm = w >> 1, wn = w & 1;
  f32x4 acc[4][4] = {};
  for (int k0 = 0; k0 < 512; k0 += 64) {
    __syncthreads();
#pragma unroll
    for (int i = 0; i < 4; ++i) {
      int idx = t + i * 256;
      int row = idx >> 3, seg = idx & 7;
      *(bf16x8*)&As[row * 72 + seg * 8] = *(const bf16x8*)&A[(size_t)(m0 + row) * 512 + k0 + seg * 8];
      *(bf16x8*)&Bs[row * 72 + seg * 8] = *(const bf16x8*)&Wt[(size_t)(n0 + row) * 512 + k0 + seg * 8];
    }
    __syncthreads();
#pragma unroll
    for (int ks = 0; ks < 2; ++ks) {
      bf16x8 af[4], bb[4];
#pragma unroll
      for (int i = 0; i < 4; ++i) {
        af[i] = *(const bf16x8*)&As[(wm * 64 + i * 16 + (lane & 15)) * 72 + ks * 32 + (lane >> 4) * 8];
        bb[i] = *(const bf16x8*)&Bs[(wn * 64 + i * 16 + (lane & 15)) * 72 + ks * 32 + (lane >> 4) * 8];
      }
#pragma unroll
      for (int i = 0; i < 4; ++i)
#pragma unroll
        for (int j = 0; j < 4; ++j)
          acc[i][j] = __builtin_amdgcn_mfma_f32_16x16x32_bf16(af[i], bb[j], acc[i][j], 0, 0, 0);
    }
  }
#pragma unroll
  for (int i = 0; i < 4; ++i) {
    int rowb = m0 + wm * 64 + i * 16 + ((lane >> 4) << 2);
#pragma unroll
    for (int j = 0; j < 4; ++j) {
      int col = n0 + wn * 64 + j * 16 + (lane & 15);
      float bv = bias[col];
#pragma unroll
      for (int r = 0; r < 4; ++r)
        Cout[(size_t)(rowb + r) * N + col] = f2bf(acc[i][j][r] + bv);
    }
  }
}

// ---------------- fused attention; block = 4 heads of one 64-token bin (2 blocks/bin).
// qkv row layout [1536]: q at col h*64, k at 512+h*64, v at 1024+h*64.
__global__ __launch_bounds__(256) void k_attn(const unsigned short* __restrict__ qkv,
    const float* __restrict__ td, const int* __restrict__ validv,
    const float* __restrict__ temb, unsigned short* __restrict__ ctx) {
  __shared__ float bias_s[4][64];
  __shared__ int valid_s[64];
  __shared__ unsigned short P_s[4][64][72];
  __shared__ unsigned short Vt_s[4][64][72];
  int blk = blockIdx.x >> 1, hg = blockIdx.x & 1;
  int t = threadIdx.x, hl = t >> 6, lane = t & 63;
  int h = hg * 4 + hl;
  size_t base = (size_t)blk * 64;
  if (t < 64) {
    valid_s[t] = (validv[base + t] != 0) ? 1 : 0;
    int tb = (int)td[base + t];
    tb = min(max(tb, 0), 999);
#pragma unroll
    for (int hh = 0; hh < 4; ++hh) bias_s[hh][t] = temb[tb * 8 + hg * 4 + hh];
  }
  {  // stage V transposed: Vt[feat][key]; lane = key
    const unsigned short* vp = qkv + (base + lane) * 1536 + 1024 + h * 64;
#pragma unroll
    for (int f8 = 0; f8 < 8; ++f8) {
      bf16x8 v8 = *(const bf16x8*)(vp + f8 * 8);
#pragma unroll
      for (int j = 0; j < 8; ++j) Vt_s[hl][f8 * 8 + j][lane] = (unsigned short)v8[j];
    }
  }
  __syncthreads();
  bf16x8 qa[2][4], kb[2][4];
#pragma unroll
  for (int ks = 0; ks < 2; ++ks)
#pragma unroll
    for (int i = 0; i < 4; ++i) {
      int row = i * 16 + (lane & 15);
      int kk = ks * 32 + (lane >> 4) * 8;
      qa[ks][i] = *(const bf16x8*)&qkv[(base + row) * 1536 + h * 64 + kk];
      kb[ks][i] = *(const bf16x8*)&qkv[(base + row) * 1536 + 512 + h * 64 + kk];
    }
  f32x4 acc[4][4] = {};
#pragma unroll
  for (int ks = 0; ks < 2; ++ks)
#pragma unroll
    for (int i = 0; i < 4; ++i)
#pragma unroll
      for (int j = 0; j < 4; ++j)
        acc[i][j] = __builtin_amdgcn_mfma_f32_16x16x32_bf16(qa[ks][i], kb[ks][j], acc[i][j], 0, 0, 0);
  // masked+biased softmax over keys; row r held by 16-lane group, 4 frag-cols
#pragma unroll
  for (int i = 0; i < 4; ++i) {
#pragma unroll
    for (int r = 0; r < 4; ++r) {
      float sv[4];
#pragma unroll
      for (int j = 0; j < 4; ++j) {
        int key = j * 16 + (lane & 15);
        float s = acc[i][j][r] * 0.125f;
        sv[j] = valid_s[key] ? (s + bias_s[hl][key]) : -1e9f;
      }
      float m = fmaxf(fmaxf(sv[0], sv[1]), fmaxf(sv[2], sv[3]));
#pragma unroll
      for (int off = 1; off < 16; off <<= 1) m = fmaxf(m, __shfl_xor(m, off, 64));
      float p[4], sum = 0.f;
#pragma unroll
      for (int j = 0; j < 4; ++j) { p[j] = __expf(sv[j] - m); sum += p[j]; }
#pragma unroll
      for (int off = 1; off < 16; off <<= 1) sum += __shfl_xor(sum, off, 64);
      float inv = 1.f / sum;
      int row = i * 16 + ((lane >> 4) << 2) + r;
#pragma unroll
      for (int j = 0; j < 4; ++j) P_s[hl][row][j * 16 + (lane & 15)] = f2bf(p[j] * inv);
    }
  }
  __syncthreads();
  f32x4 acc2[4][4] = {};
#pragma unroll
  for (int ks = 0; ks < 2; ++ks) {
    bf16x8 pa[4], vb[4];
    int kk = ks * 32 + (lane >> 4) * 8;
#pragma unroll
    for (int i = 0; i < 4; ++i) {
      pa[i] = *(const bf16x8*)&P_s[hl][i * 16 + (lane & 15)][kk];
      vb[i] = *(const bf16x8*)&Vt_s[hl][i * 16 + (lane & 15)][kk];
    }
#pragma unroll
    for (int i = 0; i < 4; ++i)
#pragma unroll
      for (int j = 0; j < 4; ++j)
        acc2[i][j] = __builtin_amdgcn_mfma_f32_16x16x32_bf16(pa[i], vb[j], acc2[i][j], 0, 0, 0);
  }
#pragma unroll
  for (int i = 0; i < 4; ++i) {
    int rowb = i * 16 + ((lane >> 4) << 2);
#pragma unroll
    for (int j = 0; j < 4; ++j) {
      int col = h * 64 + j * 16 + (lane & 15);
#pragma unroll
      for (int r = 0; r < 4; ++r)
        ctx[(base + rowb + r) * 512 + col] = f2bf(acc2[i][j][r]);
    }
  }
}

// ---------------- LayerNorm rows (bf16 in) + masked mean-pool 64 rows -> bf16[512]
__global__ __launch_bounds__(256) void k_lnpool(const unsigned short* __restrict__ X,
    const float* __restrict__ g, const float* __restrict__ bt,
    const int* __restrict__ validv, unsigned short* __restrict__ out) {
  __shared__ float pool_s[4][512];
  __shared__ int cnt_s[4];
  int blk = blockIdx.x;
  int t = threadIdx.x, w = t >> 6, lane = t & 63;
  float gv[8], bv[8];
#pragma unroll
  for (int i = 0; i < 8; ++i) { gv[i] = g[lane * 8 + i]; bv[i] = bt[lane * 8 + i]; }
  float psum[8] = {0.f, 0.f, 0.f, 0.f, 0.f, 0.f, 0.f, 0.f};
  int cnt = 0;
  for (int r0 = 0; r0 < 16; ++r0) {
    int row = blk * 64 + w * 16 + r0;
    bf16x8 xv = *(const bf16x8*)(X + (size_t)row * 512 + lane * 8);
    float xa[8];
#pragma unroll
    for (int i = 0; i < 8; ++i) xa[i] = bf2f((unsigned short)xv[i]);
    float s = 0.f;
#pragma unroll
    for (int i = 0; i < 8; ++i) s += xa[i];
#pragma unroll
    for (int off = 1; off < 64; off <<= 1) s += __shfl_xor(s, off, 64);
    float mean = s * (1.f / 512.f);
    float vsum = 0.f;
#pragma unroll
    for (int i = 0; i < 8; ++i) { float d = xa[i] - mean; vsum += d * d; }
#pragma unroll
    for (int off = 1; off < 64; off <<= 1) vsum += __shfl_xor(vsum, off, 64);
    float rstd = rsqrtf(vsum * (1.f / 512.f) + 1e-5f);
    if (validv[row] != 0) {
      cnt++;
#pragma unroll
      for (int i = 0; i < 8; ++i) psum[i] += (xa[i] - mean) * rstd * gv[i] + bv[i];
    }
  }
#pragma unroll
  for (int i = 0; i < 8; ++i) pool_s[w][lane * 8 + i] = psum[i];
  if (lane == 0) cnt_s[w] = cnt;
  __syncthreads();
  int total = cnt_s[0] + cnt_s[1] + cnt_s[2] + cnt_s[3];
  float denom = fmaxf((float)total, 1.f);
  for (int c = t; c < 512; c += 256) {
    float v = (pool_s[0][c] + pool_s[1][c] + pool_s[2][c] + pool_s[3][c]) / denom;
    out[(size_t)blk * 512 + c] = f2bf(v);
  }
}

// ---------------- final: select last row, LN(e_g,e_bt), MLP, sigmoid. grid 8.
__global__ __launch_bounds__(256) void k_final(const unsigned short* __restrict__ proj2,
    const int* __restrict__ last_idx, const float* __restrict__ g, const float* __restrict__ bt,
    const float* __restrict__ w1, const float* __restrict__ b1,
    const float* __restrict__ w2, const float* __restrict__ b2, float* __restrict__ outp) {
  __shared__ float row_s[512];
  __shared__ float red_s[4];
  __shared__ float red2_s[4];
  int b = blockIdx.x, t = threadIdx.x;
  const unsigned short* rp = proj2 + (size_t)(b * 64 + last_idx[b]) * 512;
  float v0 = bf2f(rp[t]), v1 = bf2f(rp[t + 256]);
  float s = v0 + v1;
#pragma unroll
  for (int off = 1; off < 64; off <<= 1) s += __shfl_xor(s, off, 64);
  if ((t & 63) == 0) red_s[t >> 6] = s;
  __syncthreads();
  float mean = (red_s[0] + red_s[1] + red_s[2] + red_s[3]) * (1.f / 512.f);
  float d0 = v0 - mean, d1 = v1 - mean;
  float vs = d0 * d0 + d1 * d1;
#pragma unroll
  for (int off = 1; off < 64; off <<= 1) vs += __shfl_xor(vs, off, 64);
  if ((t & 63) == 0) red2_s[t >> 6] = vs;
  __syncthreads();
  float rstd = rsqrtf((red2_s[0] + red2_s[1] + red2_s[2] + red2_s[3]) * (1.f / 512.f) + 1e-5f);
  row_s[t]       = d0 * rstd * g[t]       + bt[t];
  row_s[t + 256] = d1 * rstd * g[t + 256] + bt[t + 256];
  __syncthreads();
  float acc = b1[t];
  for (int k = 0; k < 512; ++k) acc += row_s[k] * w1[(size_t)k * 256 + t];
  float hv = fmaxf(acc, 0.f) * w2[t];
#pragma unroll
  for (int off = 1; off < 64; off <<= 1) hv += __shfl_xor(hv, off, 64);
  if ((t & 63) == 0) red_s[t >> 6] = hv;
  __syncthreads();
  if (t == 0) {
    float o = red_s[0] + red_s[1] + red_s[2] + red_s[3] + b2[0];
    outp[b] = 1.f / (1.f + __expf(-o));
  }
}

extern "C" void kernel_launch(void* const* d_in, const int* in_sizes, int n_in,
                              void* d_out, int out_size, void* d_ws, size_t ws_size,
                              hipStream_t stream) {
  const int*   x    = (const int*)d_in[0];
  const float* td   = (const float*)d_in[1];
  const float* ee   = (const float*)d_in[2];
  const float* er   = (const float*)d_in[3];
  const float* ea   = (const float*)d_in[4];
  const float* iq_w = (const float*)d_in[5];  const float* iq_b = (const float*)d_in[6];
  const float* ik_w = (const float*)d_in[7];  const float* ik_b = (const float*)d_in[8];
  const float* iv_w = (const float*)d_in[9];  const float* iv_b = (const float*)d_in[10];
  const float* io_w = (const float*)d_in[11]; const float* io_b = (const float*)d_in[12];
  const float* eq_w = (const float*)d_in[13]; const float* eq_b = (const float*)d_in[14];
  const float* ek_w = (const float*)d_in[15]; const float* ek_b = (const float*)d_in[16];
  const float* ev_w = (const float*)d_in[17]; const float* ev_b = (const float*)d_in[18];
  const float* eo_w = (const float*)d_in[19]; const float* eo_b = (const float*)d_in[20];
  const float* i_temb = (const float*)d_in[21];
  const float* e_temb = (const float*)d_in[22];
  const float* i_g  = (const float*)d_in[23]; const float* i_bt = (const float*)d_in[24];
  const float* e_g  = (const float*)d_in[25]; const float* e_bt = (const float*)d_in[26];
  const float* w1   = (const float*)d_in[27]; const float* b1   = (const float*)d_in[28];
  const float* w2   = (const float*)d_in[29]; const float* b2   = (const float*)d_in[30];

  char* ws = (char*)d_ws;
  size_t off = 0;
  auto alloc = [&](size_t nb) { size_t r = off; off += (nb + 255) & ~(size_t)255; return r; };
  float* abs_t    = (float*)(ws + alloc((size_t)32768 * 4));
  float* bin_rel  = (float*)(ws + alloc(512 * 4));
  int*   bin_mask = (int*)(ws + alloc(512 * 4));
  int*   last_idx = (int*)(ws + alloc(64));
  unsigned short* wqkv_i = (unsigned short*)(ws + alloc((size_t)1536 * 512 * 2));
  unsigned short* wo_i   = (unsigned short*)(ws + alloc((size_t)512 * 512 * 2));
  unsigned short* wqkv_e = (unsigned short*)(ws + alloc((size_t)1536 * 512 * 2));
  unsigned short* wo_e   = (unsigned short*)(ws + alloc((size_t)512 * 512 * 2));
  float* bqkv_i = (float*)(ws + alloc(1536 * 4));
  float* bqkv_e = (float*)(ws + alloc(1536 * 4));
  unsigned short* hbuf = (unsigned short*)(ws + alloc((size_t)32768 * 512 * 2));   // h, then ctx
  char* big = ws + alloc((size_t)32768 * 1536 * 2);                                // qkv bf16, then proj bf16
  unsigned short* qkvbuf = (unsigned short*)big;
  unsigned short* projbuf = (unsigned short*)big;
  unsigned short* bin_repr = (unsigned short*)(ws + alloc((size_t)512 * 512 * 2));
  char* small = ws + alloc((size_t)512 * 1536 * 2);                                // qkv2 bf16, then proj2 bf16
  unsigned short* qkv2 = (unsigned short*)small;
  unsigned short* proj2 = (unsigned short*)small;
  unsigned short* ctx2 = (unsigned short*)(ws + alloc((size_t)512 * 512 * 2));

  // 1. pack weights (bf16, transposed) + concat qkv biases
  TPackArgs tp;
  tp.s[0] = iq_w; tp.d[0] = wqkv_i;
  tp.s[1] = ik_w; tp.d[1] = wqkv_i + (size_t)512 * 512;
  tp.s[2] = iv_w; tp.d[2] = wqkv_i + (size_t)1024 * 512;
  tp.s[3] = io_w; tp.d[3] = wo_i;
  tp.s[4] = eq_w; tp.d[4] = wqkv_e;
  tp.s[5] = ek_w; tp.d[5] = wqkv_e + (size_t)512 * 512;
  tp.s[6] = ev_w; tp.d[6] = wqkv_e + (size_t)1024 * 512;
  tp.s[7] = eo_w; tp.d[7] = wo_e;
  k_tpack8<<<512, 256, 0, stream>>>(tp);
  k_bias2<<<6, 256, 0, stream>>>(iq_b, ik_b, iv_b, eq_b, ek_b, ev_b, bqkv_i, bqkv_e);

  // 2. time features (fused cumsum + bin stats)
  k_time<<<8, 64, 0, stream>>>(td, x, abs_t, bin_rel, bin_mask, last_idx);

  // 3. embeddings -> h (bf16)
  k_embed<<<8192, 256, 0, stream>>>(x, td, abs_t, ee, er, ea, hbuf);

  // 4. intra path (256^2 8-wave GEMMs; grids 768 and 256, %8==0)
  k_gemm256<<<128 * 6, 512, 0, stream>>>(hbuf, wqkv_i, bqkv_i, qkvbuf, 1536, 6);
  k_attn<<<1024, 256, 0, stream>>>(qkvbuf, td, x, i_temb, hbuf);                   // ctx -> hbuf
  k_gemm256<<<128 * 2, 512, 0, stream>>>(hbuf, wo_i, io_b, projbuf, 512, 2);       // proj over qkv region
  k_lnpool<<<512, 256, 0, stream>>>(projbuf, i_g, i_bt, x, bin_repr);

  // 5. inter path (small: 128^2 reg-staged GEMM)
  k_gemm<<<4 * 12, 256, 0, stream>>>(bin_repr, wqkv_e, bqkv_e, qkv2, 1536, 12);
  k_attn<<<16, 256, 0, stream>>>(qkv2, bin_rel, bin_mask, e_temb, ctx2);
  k_gemm<<<4 * 4, 256, 0, stream>>>(ctx2, wo_e, eo_b, proj2, 512, 4);              // proj2 over qkv2 region

  // 6. head (fused LN + MLP + sigmoid)
  k_final<<<8, 256, 0, stream>>>(proj2, last_idx, e_g, e_bt, w1, b1, w2, b2, (float*)d_out);
}

// Round 5
// 234.219 us; speedup vs baseline: 1.4460x; 1.1394x over previous
//
#include <hip/hip_runtime.h>

// HierarchicalChronoFormer forward, MI355X (gfx950).
// B=8, S=4096, D=512, H=8, dk=64, BIN=64, NB=64, T_BINS=1000.

typedef __attribute__((ext_vector_type(8))) short bf16x8;
typedef __attribute__((ext_vector_type(4))) float f32x4;

#define DEVI __device__ __forceinline__

DEVI unsigned short f2bf(float f) {
  union { float f; unsigned u; } v; v.f = f;
  unsigned r = v.u + 0x7FFFu + ((v.u >> 16) & 1u);
  return (unsigned short)(r >> 16);
}
DEVI float bf2f(unsigned short u) {
  union { unsigned u; float f; } v; v.u = ((unsigned)u) << 16; return v.f;
}

#define GLOAD_LDS16(gp, lp) \
  __builtin_amdgcn_global_load_lds((const __attribute__((address_space(1))) void*)(gp), \
                                   (__attribute__((address_space(3))) void*)(lp), 16, 0, 0)

// ---------------- weight transpose-pack + bias concat. blocks 0..511: Wt[n][k]=bf16(W[k][n]);
// block 512: both qkv bias concats.
struct TPackArgs { const float* s[8]; unsigned short* d[8];
                   const float* bs[6]; float* bd[2]; };

__global__ __launch_bounds__(256) void k_tpack8(TPackArgs args) {
  __shared__ float tile[64][65];
  if (blockIdx.x == 512) {
    int t = threadIdx.x;
    for (int i = t; i < 1536; i += 256) {
      int sel = i >> 9, r = i & 511;
      args.bd[0][i] = args.bs[sel][r];
      args.bd[1][i] = args.bs[3 + sel][r];
    }
    return;
  }
  int mat = blockIdx.x >> 6;
  int tl = blockIdx.x & 63;
  const float* W = args.s[mat];
  unsigned short* Wt = args.d[mat];
  int n0 = (tl & 7) << 6, k0 = (tl >> 3) << 6;
  int t = threadIdx.x, j = t & 63, i0 = t >> 6;
#pragma unroll
  for (int rr = 0; rr < 16; ++rr) {
    int i = rr * 4 + i0;
    tile[i][j] = W[(size_t)(k0 + i) * 512 + n0 + j];
  }
  __syncthreads();
#pragma unroll
  for (int rr = 0; rr < 16; ++rr) {
    int i = rr * 4 + i0;
    Wt[(size_t)(n0 + i) * 512 + k0 + j] = f2bf(tile[j][i]);
  }
}

// ---------------- fused time features: lane owns bin. abs_t + bin_rel/mask/last_idx.
__global__ __launch_bounds__(64) void k_time(const float* __restrict__ td, const int* __restrict__ x,
    float* __restrict__ abs_t, float* __restrict__ bin_rel, int* __restrict__ bin_mask,
    int* __restrict__ last_idx) {
  int b = blockIdx.x, lane = threadIdx.x;            // lane = bin index
  const float* row = td + (size_t)b * 4096 + lane * 64;
  const int*   xr  = x  + (size_t)b * 4096 + lane * 64;
  float* out = abs_t + (size_t)b * 4096 + lane * 64;
  float s = 0.f;
  for (int i = 0; i < 64; ++i) s += fmaxf(row[i], 0.f);
  float pre = s;
#pragma unroll
  for (int off = 1; off < 64; off <<= 1) {
    float n = __shfl_up(pre, off, 64);
    if (lane >= off) pre += n;
  }
  float a = pre - s;                                  // exclusive prefix
  float am = 0.f; int anyv = 0;
  for (int i = 0; i < 64; ++i) {
    a += fmaxf(row[i], 0.f);
    out[i] = a;
    if (xr[i] != 0) { am = fmaxf(am, a); anyv = 1; }
  }
  float prev = __shfl_up(am, 1, 64);
  bin_rel[b * 64 + lane] = (lane == 0) ? 0.f : fmaxf(am - prev, 0.f);
  bin_mask[b * 64 + lane] = anyv;
  unsigned long long bal = __ballot(anyv != 0);
  if (lane == 0) last_idx[b] = max(__popcll(bal) - 1, 0);
}

// ---------------- h = ee[x] (0 if x==0) + emb_rel[rb] + emb_abs[ab], bf16 out
__global__ __launch_bounds__(256) void k_embed(const int* __restrict__ x, const float* __restrict__ td,
    const float* __restrict__ abs_t, const float* __restrict__ ee, const float* __restrict__ er,
    const float* __restrict__ ea, unsigned short* __restrict__ h) {
  int t = threadIdx.x;
  int tok = blockIdx.x * 4 + (t >> 6);
  int lane = t & 63;
  int c0 = lane * 8;
  int xi = x[tok];
  int rb = (int)td[tok]; rb = min(max(rb, 0), 999);
  int ab = (int)abs_t[tok]; ab = min(max(ab, 0), 999);
  const f32x4* pr = (const f32x4*)(er + (size_t)rb * 512 + c0);
  const f32x4* pa = (const f32x4*)(ea + (size_t)ab * 512 + c0);
  f32x4 s0 = pr[0] + pa[0];
  f32x4 s1 = pr[1] + pa[1];
  if (xi != 0) {
    const f32x4* pe = (const f32x4*)(ee + (size_t)xi * 512 + c0);
    s0 += pe[0]; s1 += pe[1];
  }
  bf16x8 o;
#pragma unroll
  for (int i = 0; i < 4; ++i) { o[i] = (short)f2bf(s0[i]); o[4 + i] = (short)f2bf(s1[i]); }
  *(bf16x8*)(h + (size_t)tok * 512 + c0) = o;
}

// ---------------- big GEMM: C[M,N] = A[M,512] @ Wt[N,512]^T + bias, bf16 out.
// m201-rhythm port: 256x256 tile, BK=32, 16 K-tiles, 4 LDS buffers (depth-3 prefetch),
// 8 waves (2Mx4N). Per K-tile: [vmcnt(8); barrier] + 2 phases of
// {ds_read 8/4 + stage 2 gload + barrier + lgkmcnt(0) + setprio(1) 16 MFMA}.
// 128B-superrow XOR swizzle, linear gload_lds dest + pre-swizzled source (T2 rule 21).
DEVI bf16x8 lds_frag32(const unsigned short* buf, int r, int g) {
  int sr = r >> 1;
  int slot = (((r & 1) << 2) | g) ^ (sr & 7);
  return *(const bf16x8*)&buf[sr * 64 + slot * 8];
}

__global__ __launch_bounds__(512, 2) void k_gemm256(const unsigned short* __restrict__ A,
    const unsigned short* __restrict__ Wt, const float* __restrict__ bias,
    unsigned short* __restrict__ Cout, int N, int tiles_n) {
  __shared__ unsigned short lds[4][2][256 * 32];  // 4 bufs x {A,B} x 16KB = 128KB
  int bid = blockIdx.x;
  { int q = (int)gridDim.x >> 3; bid = (bid & 7) * q + (bid >> 3); }  // grid % 8 == 0
  int by = bid / tiles_n, bx = bid % tiles_n;
  int m0 = by << 8, n0 = bx << 8;
  int t = threadIdx.x;
  int lane = t & 63, w = t >> 6;
  int wm = w >> 2, wn = w & 3;            // wave tile: rows wm*128..+127, cols wn*64..+63
  int l15 = lane & 15, l4 = lane >> 4;

  // stage half (2 gloads): matrix mat of K-tile kt. LDS dest linear in granule index;
  // global source pre-swizzled (involution matches lds_frag32).
  auto stageA = [&](int kt) {
    int k0 = kt << 5;
    unsigned short* dst = &lds[kt & 3][0][0];
#pragma unroll
    for (int l = 0; l < 2; ++l) {
      int pos = l * 512 + t;
      int sr = pos >> 3, slot = pos & 7;
      int gp = slot ^ (sr & 7);
      int row = sr * 2 + (gp >> 2);
      GLOAD_LDS16(&A[(size_t)(m0 + row) * 512 + k0 + (gp & 3) * 8], dst + pos * 8);
    }
  };
  auto stageB = [&](int kt) {
    int k0 = kt << 5;
    unsigned short* dst = &lds[kt & 3][1][0];
#pragma unroll
    for (int l = 0; l < 2; ++l) {
      int pos = l * 512 + t;
      int sr = pos >> 3, slot = pos & 7;
      int gp = slot ^ (sr & 7);
      int row = sr * 2 + (gp >> 2);
      GLOAD_LDS16(&Wt[(size_t)(n0 + row) * 512 + k0 + (gp & 3) * 8], dst + pos * 8);
    }
  };

  f32x4 acc[8][4] = {};
  stageA(0); stageB(0);
  stageA(1); stageB(1);
  stageA(2); stageB(2);

  for (int kt = 0; kt < 16; ++kt) {
    // tile-top gate: buf[kt&3] landed block-wide (all waves vmcnt'ed before barrier)
    if (kt < 14)       asm volatile("s_waitcnt vmcnt(8)" ::: "memory");
    else if (kt == 14) asm volatile("s_waitcnt vmcnt(4)" ::: "memory");
    else               asm volatile("s_waitcnt vmcnt(0)" ::: "memory");
    __builtin_amdgcn_s_barrier();
    const unsigned short* As = &lds[kt & 3][0][0];
    const unsigned short* Bs = &lds[kt & 3][1][0];

    // ---- phase A: rows 0..63 of wave tile x 64 cols
    bf16x8 af[4], bb[4];
#pragma unroll
    for (int i = 0; i < 4; ++i) af[i] = lds_frag32(As, wm * 128 + i * 16 + l15, l4);
#pragma unroll
    for (int j = 0; j < 4; ++j) bb[j] = lds_frag32(Bs, wn * 64 + j * 16 + l15, l4);
    if (kt < 13) stageA(kt + 3);
    __builtin_amdgcn_sched_barrier(0);
    __builtin_amdgcn_s_barrier();
    asm volatile("s_waitcnt lgkmcnt(0)" ::: "memory");
    __builtin_amdgcn_sched_barrier(0);
    __builtin_amdgcn_s_setprio(1);
#pragma unroll
    for (int i = 0; i < 4; ++i)
#pragma unroll
      for (int j = 0; j < 4; ++j)
        acc[i][j] = __builtin_amdgcn_mfma_f32_16x16x32_bf16(af[i], bb[j], acc[i][j], 0, 0, 0);
    __builtin_amdgcn_s_setprio(0);

    // ---- phase B: rows 64..127 of wave tile x 64 cols (bb reused from regs)
    bf16x8 ah[4];
#pragma unroll
    for (int i = 0; i < 4; ++i) ah[i] = lds_frag32(As, wm * 128 + 64 + i * 16 + l15, l4);
    if (kt < 13) stageB(kt + 3);
    __builtin_amdgcn_sched_barrier(0);
    __builtin_amdgcn_s_barrier();
    asm volatile("s_waitcnt lgkmcnt(0)" ::: "memory");
    __builtin_amdgcn_sched_barrier(0);
    __builtin_amdgcn_s_setprio(1);
#pragma unroll
    for (int i = 0; i < 4; ++i)
#pragma unroll
      for (int j = 0; j < 4; ++j)
        acc[4 + i][j] = __builtin_amdgcn_mfma_f32_16x16x32_bf16(ah[i], bb[j], acc[4 + i][j], 0, 0, 0);
    __builtin_amdgcn_s_setprio(0);
    // no trailing barrier: next tile-top [vmcnt; barrier] orders buf reuse; each wave's
    // lgkmcnt(0) before its MFMA guarantees its LDS reads of this buf are done.
  }
  // epilogue: bias + bf16 store
#pragma unroll
  for (int i = 0; i < 8; ++i) {
    int rowb = m0 + wm * 128 + i * 16 + (l4 << 2);
#pragma unroll
    for (int j = 0; j < 4; ++j) {
      int col = n0 + wn * 64 + j * 16 + l15;
      float bv = bias[col];
#pragma unroll
      for (int r = 0; r < 4; ++r)
        Cout[(size_t)(rowb + r) * N + col] = f2bf(acc[i][j][r] + bv);
    }
  }
}

// ---------------- small GEMM (inter path): 128x128 tile, reg-staged padded LDS.
__global__ __launch_bounds__(256) void k_gemm(const unsigned short* __restrict__ A,
    const unsigned short* __restrict__ Wt, const float* __restrict__ bias,
    unsigned short* __restrict__ Cout, int N, int tiles_n) {
  __shared__ unsigned short As[128 * 72];
  __shared__ unsigned short Bs[128 * 72];
  int bx = blockIdx.x % tiles_n;
  int by = blockIdx.x / tiles_n;
  int m0 = by << 7, n0 = bx << 7;
  int t = threadIdx.x;
  int lane = t & 63, w = t >> 6;
  int wm = w >> 1, wn = w & 1;
  f32x4 acc[4][4] = {};
  for (int k0 = 0; k0 < 512; k0 += 64) {
    __syncthreads();
#pragma unroll
    for (int i = 0; i < 4; ++i) {
      int idx = t + i * 256;
      int row = idx >> 3, seg = idx & 7;
      *(bf16x8*)&As[row * 72 + seg * 8] = *(const bf16x8*)&A[(size_t)(m0 + row) * 512 + k0 + seg * 8];
      *(bf16x8*)&Bs[row * 72 + seg * 8] = *(const bf16x8*)&Wt[(size_t)(n0 + row) * 512 + k0 + seg * 8];
    }
    __syncthreads();
#pragma unroll
    for (int ks = 0; ks < 2; ++ks) {
      bf16x8 af[4], bb[4];
#pragma unroll
      for (int i = 0; i < 4; ++i) {
        af[i] = *(const bf16x8*)&As[(wm * 64 + i * 16 + (lane & 15)) * 72 + ks * 32 + (lane >> 4) * 8];
        bb[i] = *(const bf16x8*)&Bs[(wn * 64 + i * 16 + (lane & 15)) * 72 + ks * 32 + (lane >> 4) * 8];
      }
#pragma unroll
      for (int i = 0; i < 4; ++i)
#pragma unroll
        for (int j = 0; j < 4; ++j)
          acc[i][j] = __builtin_amdgcn_mfma_f32_16x16x32_bf16(af[i], bb[j], acc[i][j], 0, 0, 0);
    }
  }
#pragma unroll
  for (int i = 0; i < 4; ++i) {
    int rowb = m0 + wm * 64 + i * 16 + ((lane >> 4) << 2);
#pragma unroll
    for (int j = 0; j < 4; ++j) {
      int col = n0 + wn * 64 + j * 16 + (lane & 15);
      float bv = bias[col];
#pragma unroll
      for (int r = 0; r < 4; ++r)
        Cout[(size_t)(rowb + r) * N + col] = f2bf(acc[i][j][r] + bv);
    }
  }
}

// ---------------- fused attention; block = 4 heads of one 64-token bin (2 blocks/bin).
// qkv row layout [1536]: q at col h*64, k at 512+h*64, v at 1024+h*64.
__global__ __launch_bounds__(256) void k_attn(const unsigned short* __restrict__ qkv,
    const float* __restrict__ td, const int* __restrict__ validv,
    const float* __restrict__ temb, unsigned short* __restrict__ ctx) {
  __shared__ float bias_s[4][64];
  __shared__ int valid_s[64];
  __shared__ unsigned short P_s[4][64][72];
  __shared__ unsigned short Vt_s[4][64][72];
  int blk = blockIdx.x >> 1, hg = blockIdx.x & 1;
  int t = threadIdx.x, hl = t >> 6, lane = t & 63;
  int h = hg * 4 + hl;
  size_t base = (size_t)blk * 64;
  if (t < 64) {
    valid_s[t] = (validv[base + t] != 0) ? 1 : 0;
    int tb = (int)td[base + t];
    tb = min(max(tb, 0), 999);
#pragma unroll
    for (int hh = 0; hh < 4; ++hh) bias_s[hh][t] = temb[tb * 8 + hg * 4 + hh];
  }
  {  // stage V transposed: Vt[feat][key]; lane = key
    const unsigned short* vp = qkv + (base + lane) * 1536 + 1024 + h * 64;
#pragma unroll
    for (int f8 = 0; f8 < 8; ++f8) {
      bf16x8 v8 = *(const bf16x8*)(vp + f8 * 8);
#pragma unroll
      for (int j = 0; j < 8; ++j) Vt_s[hl][f8 * 8 + j][lane] = (unsigned short)v8[j];
    }
  }
  __syncthreads();
  bf16x8 qa[2][4], kb[2][4];
#pragma unroll
  for (int ks = 0; ks < 2; ++ks)
#pragma unroll
    for (int i = 0; i < 4; ++i) {
      int row = i * 16 + (lane & 15);
      int kk = ks * 32 + (lane >> 4) * 8;
      qa[ks][i] = *(const bf16x8*)&qkv[(base + row) * 1536 + h * 64 + kk];
      kb[ks][i] = *(const bf16x8*)&qkv[(base + row) * 1536 + 512 + h * 64 + kk];
    }
  f32x4 acc[4][4] = {};
#pragma unroll
  for (int ks = 0; ks < 2; ++ks)
#pragma unroll
    for (int i = 0; i < 4; ++i)
#pragma unroll
      for (int j = 0; j < 4; ++j)
        acc[i][j] = __builtin_amdgcn_mfma_f32_16x16x32_bf16(qa[ks][i], kb[ks][j], acc[i][j], 0, 0, 0);
  // masked+biased softmax over keys; row r held by 16-lane group, 4 frag-cols
#pragma unroll
  for (int i = 0; i < 4; ++i) {
#pragma unroll
    for (int r = 0; r < 4; ++r) {
      float sv[4];
#pragma unroll
      for (int j = 0; j < 4; ++j) {
        int key = j * 16 + (lane & 15);
        float s = acc[i][j][r] * 0.125f;
        sv[j] = valid_s[key] ? (s + bias_s[hl][key]) : -1e9f;
      }
      float m = fmaxf(fmaxf(sv[0], sv[1]), fmaxf(sv[2], sv[3]));
#pragma unroll
      for (int off = 1; off < 16; off <<= 1) m = fmaxf(m, __shfl_xor(m, off, 64));
      float p[4], sum = 0.f;
#pragma unroll
      for (int j = 0; j < 4; ++j) { p[j] = __expf(sv[j] - m); sum += p[j]; }
#pragma unroll
      for (int off = 1; off < 16; off <<= 1) sum += __shfl_xor(sum, off, 64);
      float inv = 1.f / sum;
      int row = i * 16 + ((lane >> 4) << 2) + r;
#pragma unroll
      for (int j = 0; j < 4; ++j) P_s[hl][row][j * 16 + (lane & 15)] = f2bf(p[j] * inv);
    }
  }
  __syncthreads();
  f32x4 acc2[4][4] = {};
#pragma unroll
  for (int ks = 0; ks < 2; ++ks) {
    bf16x8 pa[4], vb[4];
    int kk = ks * 32 + (lane >> 4) * 8;
#pragma unroll
    for (int i = 0; i < 4; ++i) {
      pa[i] = *(const bf16x8*)&P_s[hl][i * 16 + (lane & 15)][kk];
      vb[i] = *(const bf16x8*)&Vt_s[hl][i * 16 + (lane & 15)][kk];
    }
#pragma unroll
    for (int i = 0; i < 4; ++i)
#pragma unroll
      for (int j = 0; j < 4; ++j)
        acc2[i][j] = __builtin_amdgcn_mfma_f32_16x16x32_bf16(pa[i], vb[j], acc2[i][j], 0, 0, 0);
  }
#pragma unroll
  for (int i = 0; i < 4; ++i) {
    int rowb = i * 16 + ((lane >> 4) << 2);
#pragma unroll
    for (int j = 0; j < 4; ++j) {
      int col = h * 64 + j * 16 + (lane & 15);
#pragma unroll
      for (int r = 0; r < 4; ++r)
        ctx[(base + rowb + r) * 512 + col] = f2bf(acc2[i][j][r]);
    }
  }
}

// ---------------- LayerNorm rows (bf16 in) + masked mean-pool 64 rows -> bf16[512]
__global__ __launch_bounds__(256) void k_lnpool(const unsigned short* __restrict__ X,
    const float* __restrict__ g, const float* __restrict__ bt,
    const int* __restrict__ validv, unsigned short* __restrict__ out) {
  __shared__ float pool_s[4][512];
  __shared__ int cnt_s[4];
  int blk = blockIdx.x;
  int t = threadIdx.x, w = t >> 6, lane = t & 63;
  float gv[8], bv[8];
#pragma unroll
  for (int i = 0; i < 8; ++i) { gv[i] = g[lane * 8 + i]; bv[i] = bt[lane * 8 + i]; }
  float psum[8] = {0.f, 0.f, 0.f, 0.f, 0.f, 0.f, 0.f, 0.f};
  int cnt = 0;
  for (int r0 = 0; r0 < 16; ++r0) {
    int row = blk * 64 + w * 16 + r0;
    bf16x8 xv = *(const bf16x8*)(X + (size_t)row * 512 + lane * 8);
    float xa[8];
#pragma unroll
    for (int i = 0; i < 8; ++i) xa[i] = bf2f((unsigned short)xv[i]);
    float s = 0.f;
#pragma unroll
    for (int i = 0; i < 8; ++i) s += xa[i];
#pragma unroll
    for (int off = 1; off < 64; off <<= 1) s += __shfl_xor(s, off, 64);
    float mean = s * (1.f / 512.f);
    float vsum = 0.f;
#pragma unroll
    for (int i = 0; i < 8; ++i) { float d = xa[i] - mean; vsum += d * d; }
#pragma unroll
    for (int off = 1; off < 64; off <<= 1) vsum += __shfl_xor(vsum, off, 64);
    float rstd = rsqrtf(vsum * (1.f / 512.f) + 1e-5f);
    if (validv[row] != 0) {
      cnt++;
#pragma unroll
      for (int i = 0; i < 8; ++i) psum[i] += (xa[i] - mean) * rstd * gv[i] + bv[i];
    }
  }
#pragma unroll
  for (int i = 0; i < 8; ++i) pool_s[w][lane * 8 + i] = psum[i];
  if (lane == 0) cnt_s[w] = cnt;
  __syncthreads();
  int total = cnt_s[0] + cnt_s[1] + cnt_s[2] + cnt_s[3];
  float denom = fmaxf((float)total, 1.f);
  for (int c = t; c < 512; c += 256) {
    float v = (pool_s[0][c] + pool_s[1][c] + pool_s[2][c] + pool_s[3][c]) / denom;
    out[(size_t)blk * 512 + c] = f2bf(v);
  }
}

// ---------------- final: select last row, LN(e_g,e_bt), MLP, sigmoid. grid 8.
__global__ __launch_bounds__(256) void k_final(const unsigned short* __restrict__ proj2,
    const int* __restrict__ last_idx, const float* __restrict__ g, const float* __restrict__ bt,
    const float* __restrict__ w1, const float* __restrict__ b1,
    const float* __restrict__ w2, const float* __restrict__ b2, float* __restrict__ outp) {
  __shared__ float row_s[512];
  __shared__ float red_s[4];
  __shared__ float red2_s[4];
  int b = blockIdx.x, t = threadIdx.x;
  const unsigned short* rp = proj2 + (size_t)(b * 64 + last_idx[b]) * 512;
  float v0 = bf2f(rp[t]), v1 = bf2f(rp[t + 256]);
  float s = v0 + v1;
#pragma unroll
  for (int off = 1; off < 64; off <<= 1) s += __shfl_xor(s, off, 64);
  if ((t & 63) == 0) red_s[t >> 6] = s;
  __syncthreads();
  float mean = (red_s[0] + red_s[1] + red_s[2] + red_s[3]) * (1.f / 512.f);
  float d0 = v0 - mean, d1 = v1 - mean;
  float vs = d0 * d0 + d1 * d1;
#pragma unroll
  for (int off = 1; off < 64; off <<= 1) vs += __shfl_xor(vs, off, 64);
  if ((t & 63) == 0) red2_s[t >> 6] = vs;
  __syncthreads();
  float rstd = rsqrtf((red2_s[0] + red2_s[1] + red2_s[2] + red2_s[3]) * (1.f / 512.f) + 1e-5f);
  row_s[t]       = d0 * rstd * g[t]       + bt[t];
  row_s[t + 256] = d1 * rstd * g[t + 256] + bt[t + 256];
  __syncthreads();
  float acc = b1[t];
  for (int k = 0; k < 512; ++k) acc += row_s[k] * w1[(size_t)k * 256 + t];
  float hv = fmaxf(acc, 0.f) * w2[t];
#pragma unroll
  for (int off = 1; off < 64; off <<= 1) hv += __shfl_xor(hv, off, 64);
  if ((t & 63) == 0) red_s[t >> 6] = hv;
  __syncthreads();
  if (t == 0) {
    float o = red_s[0] + red_s[1] + red_s[2] + red_s[3] + b2[0];
    outp[b] = 1.f / (1.f + __expf(-o));
  }
}

extern "C" void kernel_launch(void* const* d_in, const int* in_sizes, int n_in,
                              void* d_out, int out_size, void* d_ws, size_t ws_size,
                              hipStream_t stream) {
  const int*   x    = (const int*)d_in[0];
  const float* td   = (const float*)d_in[1];
  const float* ee   = (const float*)d_in[2];
  const float* er   = (const float*)d_in[3];
  const float* ea   = (const float*)d_in[4];
  const float* iq_w = (const float*)d_in[5];  const float* iq_b = (const float*)d_in[6];
  const float* ik_w = (const float*)d_in[7];  const float* ik_b = (const float*)d_in[8];
  const float* iv_w = (const float*)d_in[9];  const float* iv_b = (const float*)d_in[10];
  const float* io_w = (const float*)d_in[11]; const float* io_b = (const float*)d_in[12];
  const float* eq_w = (const float*)d_in[13]; const float* eq_b = (const float*)d_in[14];
  const float* ek_w = (const float*)d_in[15]; const float* ek_b = (const float*)d_in[16];
  const float* ev_w = (const float*)d_in[17]; const float* ev_b = (const float*)d_in[18];
  const float* eo_w = (const float*)d_in[19]; const float* eo_b = (const float*)d_in[20];
  const float* i_temb = (const float*)d_in[21];
  const float* e_temb = (const float*)d_in[22];
  const float* i_g  = (const float*)d_in[23]; const float* i_bt = (const float*)d_in[24];
  const float* e_g  = (const float*)d_in[25]; const float* e_bt = (const float*)d_in[26];
  const float* w1   = (const float*)d_in[27]; const float* b1   = (const float*)d_in[28];
  const float* w2   = (const float*)d_in[29]; const float* b2   = (const float*)d_in[30];

  char* ws = (char*)d_ws;
  size_t off = 0;
  auto alloc = [&](size_t nb) { size_t r = off; off += (nb + 255) & ~(size_t)255; return r; };
  float* abs_t    = (float*)(ws + alloc((size_t)32768 * 4));
  float* bin_rel  = (float*)(ws + alloc(512 * 4));
  int*   bin_mask = (int*)(ws + alloc(512 * 4));
  int*   last_idx = (int*)(ws + alloc(64));
  unsigned short* wqkv_i = (unsigned short*)(ws + alloc((size_t)1536 * 512 * 2));
  unsigned short* wo_i   = (unsigned short*)(ws + alloc((size_t)512 * 512 * 2));
  unsigned short* wqkv_e = (unsigned short*)(ws + alloc((size_t)1536 * 512 * 2));
  unsigned short* wo_e   = (unsigned short*)(ws + alloc((size_t)512 * 512 * 2));
  float* bqkv_i = (float*)(ws + alloc(1536 * 4));
  float* bqkv_e = (float*)(ws + alloc(1536 * 4));
  unsigned short* hbuf = (unsigned short*)(ws + alloc((size_t)32768 * 512 * 2));   // h, then ctx
  char* big = ws + alloc((size_t)32768 * 1536 * 2);                                // qkv bf16, then proj bf16
  unsigned short* qkvbuf = (unsigned short*)big;
  unsigned short* projbuf = (unsigned short*)big;
  unsigned short* bin_repr = (unsigned short*)(ws + alloc((size_t)512 * 512 * 2));
  char* small = ws + alloc((size_t)512 * 1536 * 2);                                // qkv2 bf16, then proj2 bf16
  unsigned short* qkv2 = (unsigned short*)small;
  unsigned short* proj2 = (unsigned short*)small;
  unsigned short* ctx2 = (unsigned short*)(ws + alloc((size_t)512 * 512 * 2));

  // 1. pack weights (bf16, transposed) + concat qkv biases (block 512)
  TPackArgs tp;
  tp.s[0] = iq_w; tp.d[0] = wqkv_i;
  tp.s[1] = ik_w; tp.d[1] = wqkv_i + (size_t)512 * 512;
  tp.s[2] = iv_w; tp.d[2] = wqkv_i + (size_t)1024 * 512;
  tp.s[3] = io_w; tp.d[3] = wo_i;
  tp.s[4] = eq_w; tp.d[4] = wqkv_e;
  tp.s[5] = ek_w; tp.d[5] = wqkv_e + (size_t)512 * 512;
  tp.s[6] = ev_w; tp.d[6] = wqkv_e + (size_t)1024 * 512;
  tp.s[7] = eo_w; tp.d[7] = wo_e;
  tp.bs[0] = iq_b; tp.bs[1] = ik_b; tp.bs[2] = iv_b;
  tp.bs[3] = eq_b; tp.bs[4] = ek_b; tp.bs[5] = ev_b;
  tp.bd[0] = bqkv_i; tp.bd[1] = bqkv_e;
  k_tpack8<<<513, 256, 0, stream>>>(tp);

  // 2. time features (lane-owns-bin scan + bin stats)
  k_time<<<8, 64, 0, stream>>>(td, x, abs_t, bin_rel, bin_mask, last_idx);

  // 3. embeddings -> h (bf16)
  k_embed<<<8192, 256, 0, stream>>>(x, td, abs_t, ee, er, ea, hbuf);

  // 4. intra path (256^2 8-wave BK=32 depth-3 GEMMs; grids 768 and 256, %8==0)
  k_gemm256<<<128 * 6, 512, 0, stream>>>(hbuf, wqkv_i, bqkv_i, qkvbuf, 1536, 6);
  k_attn<<<1024, 256, 0, stream>>>(qkvbuf, td, x, i_temb, hbuf);                   // ctx -> hbuf
  k_gemm256<<<128 * 2, 512, 0, stream>>>(hbuf, wo_i, io_b, projbuf, 512, 2);       // proj over qkv region
  k_lnpool<<<512, 256, 0, stream>>>(projbuf, i_g, i_bt, x, bin_repr);

  // 5. inter path (small: 128^2 reg-staged GEMM)
  k_gemm<<<4 * 12, 256, 0, stream>>>(bin_repr, wqkv_e, bqkv_e, qkv2, 1536, 12);
  k_attn<<<16, 256, 0, stream>>>(qkv2, bin_rel, bin_mask, e_temb, ctx2);
  k_gemm<<<4 * 4, 256, 0, stream>>>(ctx2, wo_e, eo_b, proj2, 512, 4);              // proj2 over qkv2 region

  // 6. head (fused LN + MLP + sigmoid)
  k_final<<<8, 256, 0, stream>>>(proj2, last_idx, e_g, e_bt, w1, b1, w2, b2, (float*)d_out);
}

// Round 6
// 231.117 us; speedup vs baseline: 1.4654x; 1.0134x over previous
//
#include <hip/hip_runtime.h>

// HierarchicalChronoFormer forward, MI355X (gfx950).
// B=8, S=4096, D=512, H=8, dk=64, BIN=64, NB=64, T_BINS=1000.

typedef __attribute__((ext_vector_type(8))) short bf16x8;
typedef __attribute__((ext_vector_type(4))) float f32x4;

#define DEVI __device__ __forceinline__

DEVI unsigned short f2bf(float f) {
  union { float f; unsigned u; } v; v.f = f;
  unsigned r = v.u + 0x7FFFu + ((v.u >> 16) & 1u);
  return (unsigned short)(r >> 16);
}
DEVI float bf2f(unsigned short u) {
  union { unsigned u; float f; } v; v.u = ((unsigned)u) << 16; return v.f;
}

#define GLOAD_LDS16(gp, lp) \
  __builtin_amdgcn_global_load_lds((const __attribute__((address_space(1))) void*)(gp), \
                                   (__attribute__((address_space(3))) void*)(lp), 16, 0, 0)

// ---------------- weight transpose-pack + bias concat.
struct TPackArgs { const float* s[8]; unsigned short* d[8];
                   const float* bs[6]; float* bd[2]; };

__global__ __launch_bounds__(256) void k_tpack8(TPackArgs args) {
  __shared__ float tile[64][65];
  if (blockIdx.x == 512) {
    int t = threadIdx.x;
    for (int i = t; i < 1536; i += 256) {
      int sel = i >> 9, r = i & 511;
      args.bd[0][i] = args.bs[sel][r];
      args.bd[1][i] = args.bs[3 + sel][r];
    }
    return;
  }
  int mat = blockIdx.x >> 6;
  int tl = blockIdx.x & 63;
  const float* W = args.s[mat];
  unsigned short* Wt = args.d[mat];
  int n0 = (tl & 7) << 6, k0 = (tl >> 3) << 6;
  int t = threadIdx.x, j = t & 63, i0 = t >> 6;
#pragma unroll
  for (int rr = 0; rr < 16; ++rr) {
    int i = rr * 4 + i0;
    tile[i][j] = W[(size_t)(k0 + i) * 512 + n0 + j];
  }
  __syncthreads();
#pragma unroll
  for (int rr = 0; rr < 16; ++rr) {
    int i = rr * 4 + i0;
    Wt[(size_t)(n0 + i) * 512 + k0 + j] = f2bf(tile[j][i]);
  }
}

// ---------------- fused time features: lane owns bin.
__global__ __launch_bounds__(64) void k_time(const float* __restrict__ td, const int* __restrict__ x,
    float* __restrict__ abs_t, float* __restrict__ bin_rel, int* __restrict__ bin_mask,
    int* __restrict__ last_idx) {
  int b = blockIdx.x, lane = threadIdx.x;
  const float* row = td + (size_t)b * 4096 + lane * 64;
  const int*   xr  = x  + (size_t)b * 4096 + lane * 64;
  float* out = abs_t + (size_t)b * 4096 + lane * 64;
  float s = 0.f;
  for (int i = 0; i < 64; ++i) s += fmaxf(row[i], 0.f);
  float pre = s;
#pragma unroll
  for (int off = 1; off < 64; off <<= 1) {
    float n = __shfl_up(pre, off, 64);
    if (lane >= off) pre += n;
  }
  float a = pre - s;
  float am = 0.f; int anyv = 0;
  for (int i = 0; i < 64; ++i) {
    a += fmaxf(row[i], 0.f);
    out[i] = a;
    if (xr[i] != 0) { am = fmaxf(am, a); anyv = 1; }
  }
  float prev = __shfl_up(am, 1, 64);
  bin_rel[b * 64 + lane] = (lane == 0) ? 0.f : fmaxf(am - prev, 0.f);
  bin_mask[b * 64 + lane] = anyv;
  unsigned long long bal = __ballot(anyv != 0);
  if (lane == 0) last_idx[b] = max(__popcll(bal) - 1, 0);
}

// ---------------- h = ee[x] (0 if x==0) + emb_rel[rb] + emb_abs[ab], bf16 out. 16 tok/block.
__global__ __launch_bounds__(256) void k_embed(const int* __restrict__ x, const float* __restrict__ td,
    const float* __restrict__ abs_t, const float* __restrict__ ee, const float* __restrict__ er,
    const float* __restrict__ ea, unsigned short* __restrict__ h) {
  int t = threadIdx.x;
  int lane = t & 63;
  int c0 = lane * 8;
#pragma unroll
  for (int it = 0; it < 4; ++it) {
    int tok = blockIdx.x * 16 + it * 4 + (t >> 6);
    int xi = x[tok];
    int rb = (int)td[tok]; rb = min(max(rb, 0), 999);
    int ab = (int)abs_t[tok]; ab = min(max(ab, 0), 999);
    const f32x4* pr = (const f32x4*)(er + (size_t)rb * 512 + c0);
    const f32x4* pa = (const f32x4*)(ea + (size_t)ab * 512 + c0);
    f32x4 s0 = pr[0] + pa[0];
    f32x4 s1 = pr[1] + pa[1];
    if (xi != 0) {
      const f32x4* pe = (const f32x4*)(ee + (size_t)xi * 512 + c0);
      s0 += pe[0]; s1 += pe[1];
    }
    bf16x8 o;
#pragma unroll
    for (int i = 0; i < 4; ++i) { o[i] = (short)f2bf(s0[i]); o[4 + i] = (short)f2bf(s1[i]); }
    *(bf16x8*)(h + (size_t)tok * 512 + c0) = o;
  }
}

// ---------------- shared swizzle helpers (BK=32 superrow XOR, involution w/ stage)
DEVI bf16x8 lds_frag32(const unsigned short* buf, int r, int g) {
  int sr = r >> 1;
  int slot = (((r & 1) << 2) | g) ^ (sr & 7);
  return *(const bf16x8*)&buf[sr * 64 + slot * 8];
}

// ---------------- big GEMM (QKV): 256x256, BK=32, 4 LDS bufs, depth-3, 8 waves.
__global__ __launch_bounds__(512, 2) void k_gemm256(const unsigned short* __restrict__ A,
    const unsigned short* __restrict__ Wt, const float* __restrict__ bias,
    unsigned short* __restrict__ Cout, int N, int tiles_n) {
  __shared__ unsigned short lds[4][2][256 * 32];
  int bid = blockIdx.x;
  { int q = (int)gridDim.x >> 3; bid = (bid & 7) * q + (bid >> 3); }
  int by = bid / tiles_n, bx = bid % tiles_n;
  int m0 = by << 8, n0 = bx << 8;
  int t = threadIdx.x;
  int lane = t & 63, w = t >> 6;
  int wm = w >> 2, wn = w & 3;
  int l15 = lane & 15, l4 = lane >> 4;

  auto stageA = [&](int kt) {
    int k0 = kt << 5;
    unsigned short* dst = &lds[kt & 3][0][0];
#pragma unroll
    for (int l = 0; l < 2; ++l) {
      int pos = l * 512 + t;
      int sr = pos >> 3, slot = pos & 7;
      int gp = slot ^ (sr & 7);
      int row = sr * 2 + (gp >> 2);
      GLOAD_LDS16(&A[(size_t)(m0 + row) * 512 + k0 + (gp & 3) * 8], dst + pos * 8);
    }
  };
  auto stageB = [&](int kt) {
    int k0 = kt << 5;
    unsigned short* dst = &lds[kt & 3][1][0];
#pragma unroll
    for (int l = 0; l < 2; ++l) {
      int pos = l * 512 + t;
      int sr = pos >> 3, slot = pos & 7;
      int gp = slot ^ (sr & 7);
      int row = sr * 2 + (gp >> 2);
      GLOAD_LDS16(&Wt[(size_t)(n0 + row) * 512 + k0 + (gp & 3) * 8], dst + pos * 8);
    }
  };

  f32x4 acc[8][4] = {};
  stageA(0); stageB(0);
  stageA(1); stageB(1);
  stageA(2); stageB(2);

  for (int kt = 0; kt < 16; ++kt) {
    if (kt < 14)       asm volatile("s_waitcnt vmcnt(8)" ::: "memory");
    else if (kt == 14) asm volatile("s_waitcnt vmcnt(4)" ::: "memory");
    else               asm volatile("s_waitcnt vmcnt(0)" ::: "memory");
    __builtin_amdgcn_s_barrier();
    const unsigned short* As = &lds[kt & 3][0][0];
    const unsigned short* Bs = &lds[kt & 3][1][0];

    bf16x8 af[4], bb[4];
#pragma unroll
    for (int i = 0; i < 4; ++i) af[i] = lds_frag32(As, wm * 128 + i * 16 + l15, l4);
#pragma unroll
    for (int j = 0; j < 4; ++j) bb[j] = lds_frag32(Bs, wn * 64 + j * 16 + l15, l4);
    if (kt < 13) stageA(kt + 3);
    __builtin_amdgcn_s_barrier();
    asm volatile("s_waitcnt lgkmcnt(0)" ::: "memory");
    __builtin_amdgcn_sched_barrier(0);
    __builtin_amdgcn_s_setprio(1);
#pragma unroll
    for (int i = 0; i < 4; ++i)
#pragma unroll
      for (int j = 0; j < 4; ++j)
        acc[i][j] = __builtin_amdgcn_mfma_f32_16x16x32_bf16(af[i], bb[j], acc[i][j], 0, 0, 0);
    __builtin_amdgcn_s_setprio(0);

    bf16x8 ah[4];
#pragma unroll
    for (int i = 0; i < 4; ++i) ah[i] = lds_frag32(As, wm * 128 + 64 + i * 16 + l15, l4);
    if (kt < 13) stageB(kt + 3);
    __builtin_amdgcn_s_barrier();
    asm volatile("s_waitcnt lgkmcnt(0)" ::: "memory");
    __builtin_amdgcn_sched_barrier(0);
    __builtin_amdgcn_s_setprio(1);
#pragma unroll
    for (int i = 0; i < 4; ++i)
#pragma unroll
      for (int j = 0; j < 4; ++j)
        acc[4 + i][j] = __builtin_amdgcn_mfma_f32_16x16x32_bf16(ah[i], bb[j], acc[4 + i][j], 0, 0, 0);
    __builtin_amdgcn_s_setprio(0);
  }
#pragma unroll
  for (int i = 0; i < 8; ++i) {
    int rowb = m0 + wm * 128 + i * 16 + (l4 << 2);
#pragma unroll
    for (int j = 0; j < 4; ++j) {
      int col = n0 + wn * 64 + j * 16 + l15;
      float bv = bias[col];
#pragma unroll
      for (int r = 0; r < 4; ++r)
        Cout[(size_t)(rowb + r) * N + col] = f2bf(acc[i][j][r] + bv);
    }
  }
}

// ---------------- fused out-proj + LN + masked pool: proj = ctx@Wo + bo; LN; pool 2 bins.
// BM=128, BN=512 (all of Wo), BK=32. A 4-buf (32KB) + B 2-buf (64KB). 8 waves (1Mx8N).
__global__ __launch_bounds__(512, 2) void k_oproj(const unsigned short* __restrict__ ctx,
    const unsigned short* __restrict__ WoT, const float* __restrict__ bo,
    const int* __restrict__ x, const float* __restrict__ g, const float* __restrict__ bt,
    unsigned short* __restrict__ bin_repr) {
  __shared__ unsigned short ldsA[4][128 * 32];
  __shared__ unsigned short ldsB[2][512 * 32];
  int bid = blockIdx.x;
  { int q = (int)gridDim.x >> 3; bid = (bid & 7) * q + (bid >> 3); }  // grid 256 %8==0
  int m0 = bid << 7;
  int t = threadIdx.x;
  int lane = t & 63, w = t >> 6;          // w = wn (cols w*64..+63), rows 0..127 all waves
  int l15 = lane & 15, l4 = lane >> 4;

  auto stageA = [&](int kt) {
    int k0 = kt << 5;
    unsigned short* dst = &ldsA[kt & 3][0];
    int pos = t;
    int sr = pos >> 3, slot = pos & 7;
    int gp = slot ^ (sr & 7);
    int row = sr * 2 + (gp >> 2);
    GLOAD_LDS16(&ctx[(size_t)(m0 + row) * 512 + k0 + (gp & 3) * 8], dst + pos * 8);
  };
  auto stageB = [&](int kt) {
    int k0 = kt << 5;
    unsigned short* dst = &ldsB[kt & 1][0];
#pragma unroll
    for (int l = 0; l < 4; ++l) {
      int pos = l * 512 + t;
      int sr = pos >> 3, slot = pos & 7;
      int gp = slot ^ (sr & 7);
      int row = sr * 2 + (gp >> 2);
      GLOAD_LDS16(&WoT[(size_t)row * 512 + k0 + (gp & 3) * 8], dst + pos * 8);
    }
  };

  f32x4 acc[8][4] = {};
  // prologue: B0, A0, A1, A2, B1  (11 loads)
  stageB(0); stageA(0); stageA(1); stageA(2); stageB(1);

  for (int kt = 0; kt < 16; ++kt) {
    if (kt == 0)      asm volatile("s_waitcnt vmcnt(6)" ::: "memory");
    else if (kt < 14) asm volatile("s_waitcnt vmcnt(1)" ::: "memory");
    else              asm volatile("s_waitcnt vmcnt(0)" ::: "memory");
    __builtin_amdgcn_s_barrier();
    const unsigned short* As = &ldsA[kt & 3][0];
    const unsigned short* Bs = &ldsB[kt & 1][0];

    bf16x8 af[4], bb[4];
#pragma unroll
    for (int i = 0; i < 4; ++i) af[i] = lds_frag32(As, i * 16 + l15, l4);
#pragma unroll
    for (int j = 0; j < 4; ++j) bb[j] = lds_frag32(Bs, w * 64 + j * 16 + l15, l4);
    if (kt >= 1 && kt <= 14) stageB(kt + 1);
    __builtin_amdgcn_s_barrier();
    asm volatile("s_waitcnt lgkmcnt(0)" ::: "memory");
    __builtin_amdgcn_sched_barrier(0);
    __builtin_amdgcn_s_setprio(1);
#pragma unroll
    for (int i = 0; i < 4; ++i)
#pragma unroll
      for (int j = 0; j < 4; ++j)
        acc[i][j] = __builtin_amdgcn_mfma_f32_16x16x32_bf16(af[i], bb[j], acc[i][j], 0, 0, 0);
    __builtin_amdgcn_s_setprio(0);

    bf16x8 ah[4];
#pragma unroll
    for (int i = 0; i < 4; ++i) ah[i] = lds_frag32(As, 64 + i * 16 + l15, l4);
    if (kt <= 12) stageA(kt + 3);
    __builtin_amdgcn_s_barrier();
    asm volatile("s_waitcnt lgkmcnt(0)" ::: "memory");
    __builtin_amdgcn_sched_barrier(0);
    __builtin_amdgcn_s_setprio(1);
#pragma unroll
    for (int i = 0; i < 4; ++i)
#pragma unroll
      for (int j = 0; j < 4; ++j)
        acc[4 + i][j] = __builtin_amdgcn_mfma_f32_16x16x32_bf16(ah[i], bb[j], acc[4 + i][j], 0, 0, 0);
    __builtin_amdgcn_s_setprio(0);
  }

  // -------- epilogue: bias + LN (f32) + masked mean-pool of 2 bins -> bin_repr
  __syncthreads();                       // all LDS reads done; reuse ldsA region
  float* red   = (float*)&ldsA[0][0];    // [128][9]
  float* meanL = red + 128 * 9;          // [128]
  float* rstdL = meanL + 128;            // [128]
  int*   valL  = (int*)(rstdL + 128);    // [128]
  int*   cntL  = valL + 128;             // [2]

  int cols[4]; float bov[4], gv[4], bv[4];
#pragma unroll
  for (int j = 0; j < 4; ++j) {
    cols[j] = w * 64 + j * 16 + l15;
    bov[j] = bo[cols[j]]; gv[j] = g[cols[j]]; bv[j] = bt[cols[j]];
  }
  if (t < 128) {
    int v = (x[m0 + t] != 0) ? 1 : 0;
    valL[t] = v;
    unsigned long long bal = __ballot(v != 0);   // wave 0 = bin0 rows, wave 1 = bin1 rows
    if ((t & 63) == 0) cntL[t >> 6] = __popcll(bal);
  }
  // pass 1: row sums
#pragma unroll
  for (int i = 0; i < 8; ++i)
#pragma unroll
    for (int r = 0; r < 4; ++r) {
      float s = (acc[i][0][r] + bov[0]) + (acc[i][1][r] + bov[1]) +
                (acc[i][2][r] + bov[2]) + (acc[i][3][r] + bov[3]);
#pragma unroll
      for (int off = 1; off < 16; off <<= 1) s += __shfl_xor(s, off, 64);
      if (l15 == 0) red[(i * 16 + l4 * 4 + r) * 9 + w] = s;
    }
  __syncthreads();
  if (t < 128) {
    float m = 0.f;
#pragma unroll
    for (int ww = 0; ww < 8; ++ww) m += red[t * 9 + ww];
    meanL[t] = m * (1.f / 512.f);
  }
  __syncthreads();
  // pass 2: row variance
#pragma unroll
  for (int i = 0; i < 8; ++i)
#pragma unroll
    for (int r = 0; r < 4; ++r) {
      float m = meanL[i * 16 + l4 * 4 + r];
      float s = 0.f;
#pragma unroll
      for (int j = 0; j < 4; ++j) { float d = acc[i][j][r] + bov[j] - m; s += d * d; }
#pragma unroll
      for (int off = 1; off < 16; off <<= 1) s += __shfl_xor(s, off, 64);
      if (l15 == 0) red[(i * 16 + l4 * 4 + r) * 9 + w] = s;
    }
  __syncthreads();
  if (t < 128) {
    float vsum = 0.f;
#pragma unroll
    for (int ww = 0; ww < 8; ++ww) vsum += red[t * 9 + ww];
    rstdL[t] = rsqrtf(vsum * (1.f / 512.f) + 1e-5f);
  }
  __syncthreads();
  // pool: y = (val-mean)*rstd*g + bt, masked by valid row; bins = rows 0-63 / 64-127
  float p0[4] = {0.f, 0.f, 0.f, 0.f}, p1[4] = {0.f, 0.f, 0.f, 0.f};
#pragma unroll
  for (int i = 0; i < 8; ++i)
#pragma unroll
    for (int r = 0; r < 4; ++r) {
      int row = i * 16 + l4 * 4 + r;
      if (valL[row]) {
        float m = meanL[row], rs = rstdL[row];
#pragma unroll
        for (int j = 0; j < 4; ++j) {
          float y = (acc[i][j][r] + bov[j] - m) * rs * gv[j] + bv[j];
          if (i < 4) p0[j] += y; else p1[j] += y;
        }
      }
    }
#pragma unroll
  for (int j = 0; j < 4; ++j) {
    p0[j] += __shfl_xor(p0[j], 16, 64); p0[j] += __shfl_xor(p0[j], 32, 64);
    p1[j] += __shfl_xor(p1[j], 16, 64); p1[j] += __shfl_xor(p1[j], 32, 64);
  }
  float d0 = 1.f / fmaxf((float)cntL[0], 1.f);
  float d1 = 1.f / fmaxf((float)cntL[1], 1.f);
  if (l4 == 0) {
    int binr = (m0 >> 6);
#pragma unroll
    for (int j = 0; j < 4; ++j) {
      bin_repr[(size_t)binr * 512 + cols[j]]       = f2bf(p0[j] * d0);
      bin_repr[(size_t)(binr + 1) * 512 + cols[j]] = f2bf(p1[j] * d1);
    }
  }
}

// ---------------- small GEMM (inter path): 128x128 tile, reg-staged padded LDS.
__global__ __launch_bounds__(256) void k_gemm(const unsigned short* __restrict__ A,
    const unsigned short* __restrict__ Wt, const float* __restrict__ bias,
    unsigned short* __restrict__ Cout, int N, int tiles_n) {
  __shared__ unsigned short As[128 * 72];
  __shared__ unsigned short Bs[128 * 72];
  int bx = blockIdx.x % tiles_n;
  int by = blockIdx.x / tiles_n;
  int m0 = by << 7, n0 = bx << 7;
  int t = threadIdx.x;
  int lane = t & 63, w = t >> 6;
  int wm = w >> 1, wn = w & 1;
  f32x4 acc[4][4] = {};
  for (int k0 = 0; k0 < 512; k0 += 64) {
    __syncthreads();
#pragma unroll
    for (int i = 0; i < 4; ++i) {
      int idx = t + i * 256;
      int row = idx >> 3, seg = idx & 7;
      *(bf16x8*)&As[row * 72 + seg * 8] = *(const bf16x8*)&A[(size_t)(m0 + row) * 512 + k0 + seg * 8];
      *(bf16x8*)&Bs[row * 72 + seg * 8] = *(const bf16x8*)&Wt[(size_t)(n0 + row) * 512 + k0 + seg * 8];
    }
    __syncthreads();
#pragma unroll
    for (int ks = 0; ks < 2; ++ks) {
      bf16x8 af[4], bb[4];
#pragma unroll
      for (int i = 0; i < 4; ++i) {
        af[i] = *(const bf16x8*)&As[(wm * 64 + i * 16 + (lane & 15)) * 72 + ks * 32 + (lane >> 4) * 8];
        bb[i] = *(const bf16x8*)&Bs[(wn * 64 + i * 16 + (lane & 15)) * 72 + ks * 32 + (lane >> 4) * 8];
      }
#pragma unroll
      for (int i = 0; i < 4; ++i)
#pragma unroll
        for (int j = 0; j < 4; ++j)
          acc[i][j] = __builtin_amdgcn_mfma_f32_16x16x32_bf16(af[i], bb[j], acc[i][j], 0, 0, 0);
    }
  }
#pragma unroll
  for (int i = 0; i < 4; ++i) {
    int rowb = m0 + wm * 64 + i * 16 + ((lane >> 4) << 2);
#pragma unroll
    for (int j = 0; j < 4; ++j) {
      int col = n0 + wn * 64 + j * 16 + (lane & 15);
      float bv = bias[col];
#pragma unroll
      for (int r = 0; r < 4; ++r)
        Cout[(size_t)(rowb + r) * N + col] = f2bf(acc[i][j][r] + bv);
    }
  }
}

// ---------------- fused attention; block = 4 heads of one 64-token bin (2 blocks/bin).
__global__ __launch_bounds__(256) void k_attn(const unsigned short* __restrict__ qkv,
    const float* __restrict__ td, const int* __restrict__ validv,
    const float* __restrict__ temb, unsigned short* __restrict__ ctx) {
  __shared__ float bias_s[4][64];
  __shared__ int valid_s[64];
  __shared__ unsigned short P_s[4][64][72];
  __shared__ unsigned short Vt_s[4][64][72];
  int blk = blockIdx.x >> 1, hg = blockIdx.x & 1;
  int t = threadIdx.x, hl = t >> 6, lane = t & 63;
  int h = hg * 4 + hl;
  size_t base = (size_t)blk * 64;
  if (t < 64) {
    valid_s[t] = (validv[base + t] != 0) ? 1 : 0;
    int tb = (int)td[base + t];
    tb = min(max(tb, 0), 999);
#pragma unroll
    for (int hh = 0; hh < 4; ++hh) bias_s[hh][t] = temb[tb * 8 + hg * 4 + hh];
  }
  {
    const unsigned short* vp = qkv + (base + lane) * 1536 + 1024 + h * 64;
#pragma unroll
    for (int f8 = 0; f8 < 8; ++f8) {
      bf16x8 v8 = *(const bf16x8*)(vp + f8 * 8);
#pragma unroll
      for (int j = 0; j < 8; ++j) Vt_s[hl][f8 * 8 + j][lane] = (unsigned short)v8[j];
    }
  }
  __syncthreads();
  bf16x8 qa[2][4], kb[2][4];
#pragma unroll
  for (int ks = 0; ks < 2; ++ks)
#pragma unroll
    for (int i = 0; i < 4; ++i) {
      int row = i * 16 + (lane & 15);
      int kk = ks * 32 + (lane >> 4) * 8;
      qa[ks][i] = *(const bf16x8*)&qkv[(base + row) * 1536 + h * 64 + kk];
      kb[ks][i] = *(const bf16x8*)&qkv[(base + row) * 1536 + 512 + h * 64 + kk];
    }
  f32x4 acc[4][4] = {};
#pragma unroll
  for (int ks = 0; ks < 2; ++ks)
#pragma unroll
    for (int i = 0; i < 4; ++i)
#pragma unroll
      for (int j = 0; j < 4; ++j)
        acc[i][j] = __builtin_amdgcn_mfma_f32_16x16x32_bf16(qa[ks][i], kb[ks][j], acc[i][j], 0, 0, 0);
#pragma unroll
  for (int i = 0; i < 4; ++i) {
#pragma unroll
    for (int r = 0; r < 4; ++r) {
      float sv[4];
#pragma unroll
      for (int j = 0; j < 4; ++j) {
        int key = j * 16 + (lane & 15);
        float s = acc[i][j][r] * 0.125f;
        sv[j] = valid_s[key] ? (s + bias_s[hl][key]) : -1e9f;
      }
      float m = fmaxf(fmaxf(sv[0], sv[1]), fmaxf(sv[2], sv[3]));
#pragma unroll
      for (int off = 1; off < 16; off <<= 1) m = fmaxf(m, __shfl_xor(m, off, 64));
      float p[4], sum = 0.f;
#pragma unroll
      for (int j = 0; j < 4; ++j) { p[j] = __expf(sv[j] - m); sum += p[j]; }
#pragma unroll
      for (int off = 1; off < 16; off <<= 1) sum += __shfl_xor(sum, off, 64);
      float inv = 1.f / sum;
      int row = i * 16 + ((lane >> 4) << 2) + r;
#pragma unroll
      for (int j = 0; j < 4; ++j) P_s[hl][row][j * 16 + (lane & 15)] = f2bf(p[j] * inv);
    }
  }
  __syncthreads();
  f32x4 acc2[4][4] = {};
#pragma unroll
  for (int ks = 0; ks < 2; ++ks) {
    bf16x8 pa[4], vb[4];
    int kk = ks * 32 + (lane >> 4) * 8;
#pragma unroll
    for (int i = 0; i < 4; ++i) {
      pa[i] = *(const bf16x8*)&P_s[hl][i * 16 + (lane & 15)][kk];
      vb[i] = *(const bf16x8*)&Vt_s[hl][i * 16 + (lane & 15)][kk];
    }
#pragma unroll
    for (int i = 0; i < 4; ++i)
#pragma unroll
      for (int j = 0; j < 4; ++j)
        acc2[i][j] = __builtin_amdgcn_mfma_f32_16x16x32_bf16(pa[i], vb[j], acc2[i][j], 0, 0, 0);
  }
#pragma unroll
  for (int i = 0; i < 4; ++i) {
    int rowb = i * 16 + ((lane >> 4) << 2);
#pragma unroll
    for (int j = 0; j < 4; ++j) {
      int col = h * 64 + j * 16 + (lane & 15);
#pragma unroll
      for (int r = 0; r < 4; ++r)
        ctx[(base + rowb + r) * 512 + col] = f2bf(acc2[i][j][r]);
    }
  }
}

// ---------------- final: select last row, LN(e_g,e_bt), MLP, sigmoid. grid 8.
__global__ __launch_bounds__(256) void k_final(const unsigned short* __restrict__ proj2,
    const int* __restrict__ last_idx, const float* __restrict__ g, const float* __restrict__ bt,
    const float* __restrict__ w1, const float* __restrict__ b1,
    const float* __restrict__ w2, const float* __restrict__ b2, float* __restrict__ outp) {
  __shared__ float row_s[512];
  __shared__ float red_s[4];
  __shared__ float red2_s[4];
  int b = blockIdx.x, t = threadIdx.x;
  const unsigned short* rp = proj2 + (size_t)(b * 64 + last_idx[b]) * 512;
  float v0 = bf2f(rp[t]), v1 = bf2f(rp[t + 256]);
  float s = v0 + v1;
#pragma unroll
  for (int off = 1; off < 64; off <<= 1) s += __shfl_xor(s, off, 64);
  if ((t & 63) == 0) red_s[t >> 6] = s;
  __syncthreads();
  float mean = (red_s[0] + red_s[1] + red_s[2] + red_s[3]) * (1.f / 512.f);
  float d0 = v0 - mean, d1 = v1 - mean;
  float vs = d0 * d0 + d1 * d1;
#pragma unroll
  for (int off = 1; off < 64; off <<= 1) vs += __shfl_xor(vs, off, 64);
  if ((t & 63) == 0) red2_s[t >> 6] = vs;
  __syncthreads();
  float rstd = rsqrtf((red2_s[0] + red2_s[1] + red2_s[2] + red2_s[3]) * (1.f / 512.f) + 1e-5f);
  row_s[t]       = d0 * rstd * g[t]       + bt[t];
  row_s[t + 256] = d1 * rstd * g[t + 256] + bt[t + 256];
  __syncthreads();
  float acc = b1[t];
  for (int k = 0; k < 512; ++k) acc += row_s[k] * w1[(size_t)k * 256 + t];
  float hv = fmaxf(acc, 0.f) * w2[t];
#pragma unroll
  for (int off = 1; off < 64; off <<= 1) hv += __shfl_xor(hv, off, 64);
  if ((t & 63) == 0) red_s[t >> 6] = hv;
  __syncthreads();
  if (t == 0) {
    float o = red_s[0] + red_s[1] + red_s[2] + red_s[3] + b2[0];
    outp[b] = 1.f / (1.f + __expf(-o));
  }
}

extern "C" void kernel_launch(void* const* d_in, const int* in_sizes, int n_in,
                              void* d_out, int out_size, void* d_ws, size_t ws_size,
                              hipStream_t stream) {
  const int*   x    = (const int*)d_in[0];
  const float* td   = (const float*)d_in[1];
  const float* ee   = (const float*)d_in[2];
  const float* er   = (const float*)d_in[3];
  const float* ea   = (const float*)d_in[4];
  const float* iq_w = (const float*)d_in[5];  const float* iq_b = (const float*)d_in[6];
  const float* ik_w = (const float*)d_in[7];  const float* ik_b = (const float*)d_in[8];
  const float* iv_w = (const float*)d_in[9];  const float* iv_b = (const float*)d_in[10];
  const float* io_w = (const float*)d_in[11]; const float* io_b = (const float*)d_in[12];
  const float* eq_w = (const float*)d_in[13]; const float* eq_b = (const float*)d_in[14];
  const float* ek_w = (const float*)d_in[15]; const float* ek_b = (const float*)d_in[16];
  const float* ev_w = (const float*)d_in[17]; const float* ev_b = (const float*)d_in[18];
  const float* eo_w = (const float*)d_in[19]; const float* eo_b = (const float*)d_in[20];
  const float* i_temb = (const float*)d_in[21];
  const float* e_temb = (const float*)d_in[22];
  const float* i_g  = (const float*)d_in[23]; const float* i_bt = (const float*)d_in[24];
  const float* e_g  = (const float*)d_in[25]; const float* e_bt = (const float*)d_in[26];
  const float* w1   = (const float*)d_in[27]; const float* b1   = (const float*)d_in[28];
  const float* w2   = (const float*)d_in[29]; const float* b2   = (const float*)d_in[30];

  char* ws = (char*)d_ws;
  size_t off = 0;
  auto alloc = [&](size_t nb) { size_t r = off; off += (nb + 255) & ~(size_t)255; return r; };
  float* abs_t    = (float*)(ws + alloc((size_t)32768 * 4));
  float* bin_rel  = (float*)(ws + alloc(512 * 4));
  int*   bin_mask = (int*)(ws + alloc(512 * 4));
  int*   last_idx = (int*)(ws + alloc(64));
  unsigned short* wqkv_i = (unsigned short*)(ws + alloc((size_t)1536 * 512 * 2));
  unsigned short* wo_i   = (unsigned short*)(ws + alloc((size_t)512 * 512 * 2));
  unsigned short* wqkv_e = (unsigned short*)(ws + alloc((size_t)1536 * 512 * 2));
  unsigned short* wo_e   = (unsigned short*)(ws + alloc((size_t)512 * 512 * 2));
  float* bqkv_i = (float*)(ws + alloc(1536 * 4));
  float* bqkv_e = (float*)(ws + alloc(1536 * 4));
  unsigned short* hbuf = (unsigned short*)(ws + alloc((size_t)32768 * 512 * 2));   // h, then ctx
  unsigned short* qkvbuf = (unsigned short*)(ws + alloc((size_t)32768 * 1536 * 2));
  unsigned short* bin_repr = (unsigned short*)(ws + alloc((size_t)512 * 512 * 2));
  char* small = ws + alloc((size_t)512 * 1536 * 2);                                // qkv2, then proj2
  unsigned short* qkv2 = (unsigned short*)small;
  unsigned short* proj2 = (unsigned short*)small;
  unsigned short* ctx2 = (unsigned short*)(ws + alloc((size_t)512 * 512 * 2));

  // 1. pack weights + bias concats
  TPackArgs tp;
  tp.s[0] = iq_w; tp.d[0] = wqkv_i;
  tp.s[1] = ik_w; tp.d[1] = wqkv_i + (size_t)512 * 512;
  tp.s[2] = iv_w; tp.d[2] = wqkv_i + (size_t)1024 * 512;
  tp.s[3] = io_w; tp.d[3] = wo_i;
  tp.s[4] = eq_w; tp.d[4] = wqkv_e;
  tp.s[5] = ek_w; tp.d[5] = wqkv_e + (size_t)512 * 512;
  tp.s[6] = ev_w; tp.d[6] = wqkv_e + (size_t)1024 * 512;
  tp.s[7] = eo_w; tp.d[7] = wo_e;
  tp.bs[0] = iq_b; tp.bs[1] = ik_b; tp.bs[2] = iv_b;
  tp.bs[3] = eq_b; tp.bs[4] = ek_b; tp.bs[5] = ev_b;
  tp.bd[0] = bqkv_i; tp.bd[1] = bqkv_e;
  k_tpack8<<<513, 256, 0, stream>>>(tp);

  // 2. time features
  k_time<<<8, 64, 0, stream>>>(td, x, abs_t, bin_rel, bin_mask, last_idx);

  // 3. embeddings -> h
  k_embed<<<2048, 256, 0, stream>>>(x, td, abs_t, ee, er, ea, hbuf);

  // 4. intra path
  k_gemm256<<<128 * 6, 512, 0, stream>>>(hbuf, wqkv_i, bqkv_i, qkvbuf, 1536, 6);
  k_attn<<<1024, 256, 0, stream>>>(qkvbuf, td, x, i_temb, hbuf);                   // ctx -> hbuf
  k_oproj<<<256, 512, 0, stream>>>(hbuf, wo_i, io_b, x, i_g, i_bt, bin_repr);      // proj+LN+pool

  // 5. inter path
  k_gemm<<<4 * 12, 256, 0, stream>>>(bin_repr, wqkv_e, bqkv_e, qkv2, 1536, 12);
  k_attn<<<16, 256, 0, stream>>>(qkv2, bin_rel, bin_mask, e_temb, ctx2);
  k_gemm<<<4 * 4, 256, 0, stream>>>(ctx2, wo_e, eo_b, proj2, 512, 4);

  // 6. head
  k_final<<<8, 256, 0, stream>>>(proj2, last_idx, e_g, e_bt, w1, b1, w2, b2, (float*)d_out);
}